// Round 4
// baseline (2145.046 us; speedup 1.0000x reference)
//
#include <hip/hip_runtime.h>

#define B_    4
#define N_    2048
#define D_    1024
#define L_    4
#define M_    256
#define DH_   64
#define H_    16
#define BH_   64      // B_*H_
#define ROWS_ 8192    // B_*N_
#define SPLIT_ 4      // ctx GEMM k-split

typedef __bf16 bf16x8 __attribute__((ext_vector_type(8)));
typedef float  f32x4  __attribute__((ext_vector_type(4)));
typedef unsigned short u16;

__device__ __forceinline__ u16 f2b(float f){
  unsigned u = __float_as_uint(f);
  u += 0x7FFFu + ((u >> 16) & 1u);          // RNE
  return (u16)(u >> 16);
}
__device__ __forceinline__ float b2f(u16 h){ return __uint_as_float(((unsigned)h) << 16); }
__device__ __forceinline__ unsigned fkey(float x){
  unsigned u = __float_as_uint(x);
  return (u & 0x80000000u) ? ~u : (u | 0x80000000u);
}
__device__ __forceinline__ float fdec(unsigned k){
  unsigned u = (k & 0x80000000u) ? (k ^ 0x80000000u) : ~k;
  return __uint_as_float(u);
}

// global -> LDS direct, 16B per lane. LDS dest is wave-uniform base + lane*16.
__device__ __forceinline__ void gload16(const u16* g, u16* l){
  __builtin_amdgcn_global_load_lds(
      (const __attribute__((address_space(1))) void*)g,
      (__attribute__((address_space(3))) void*)l, 16, 0, 0);
}

// ---------------- fp32 -> bf16 convert ----------------
__global__ __launch_bounds__(256) void wcvt_k(const float* __restrict__ s, u16* __restrict__ d, long n){
  long i = ((long)blockIdx.x*256 + threadIdx.x)*4;
  if (i+3 < n){
    float4 v = *(const float4*)(s+i);
    d[i]=f2b(v.x); d[i+1]=f2b(v.y); d[i+2]=f2b(v.z); d[i+3]=f2b(v.w);
  } else {
    for(long j=i;j<n;j++) d[j]=f2b(s[j]);
  }
}

// ---------------- diagnostic fill ----------------
__global__ void fillf_k(float* o, long n, float v){
  long i=(long)blockIdx.x*256+threadIdx.x; if(i<n) o[i]=v;
}

// ---------------- LayerNorm: fp32 row -> bf16 row ----------------
__global__ __launch_bounds__(256) void ln_k(const float* __restrict__ x,
    const float* __restrict__ g, const float* __restrict__ bt, u16* __restrict__ h){
  int row = blockIdx.x, t = threadIdx.x;
  const float* xr = x + (long)row*D_;
  float4 v = *(const float4*)(xr + t*4);
  float s  = v.x+v.y+v.z+v.w;
  float ss = v.x*v.x+v.y*v.y+v.z*v.z+v.w*v.w;
  #pragma unroll
  for (int m=1;m<64;m<<=1){ s += __shfl_xor(s,m); ss += __shfl_xor(ss,m); }
  __shared__ float ps[4][2];
  int w=t>>6;
  if ((t&63)==0){ ps[w][0]=s; ps[w][1]=ss; }
  __syncthreads();
  s  = ps[0][0]+ps[1][0]+ps[2][0]+ps[3][0];
  ss = ps[0][1]+ps[1][1]+ps[2][1]+ps[3][1];
  float mean = s*(1.0f/D_);
  float rs = rsqrtf(ss*(1.0f/D_) - mean*mean + 1e-5f);
  int c=t*4;
  u16* hr = h + (long)row*D_;
  hr[c+0]=f2b((v.x-mean)*rs*g[c+0]+bt[c+0]);
  hr[c+1]=f2b((v.y-mean)*rs*g[c+1]+bt[c+1]);
  hr[c+2]=f2b((v.z-mean)*rs*g[c+2]+bt[c+2]);
  hr[c+3]=f2b((v.w-mean)*rs*g[c+3]+bt[c+3]);
}

// ---------------- diag[z][n] = sum_d x^2 / 16 ----------------
__global__ __launch_bounds__(256) void diagk_k(const u16* __restrict__ X, float* __restrict__ dg){
  int t=threadIdx.x, w=t>>6, lane=t&63;
  long r=(long)blockIdx.x*4+w;           // r = z*N_ + n
  int z=(int)(r>>11), n=(int)(r&2047);
  int b=z>>4, hh=z&15;
  float v=b2f(X[((long)b*N_+n)*D_ + hh*DH_ + lane]);
  float sq=v*v;
  #pragma unroll
  for (int m=1;m<64;m<<=1) sq += __shfl_xor(sq,m);
  if (lane==0) dg[r]=sq*0.0625f;
}

// ---------------- v (B,N,H,dh) -> v_t [z][d][n] ----------------
__global__ __launch_bounds__(256) void vt_k(const u16* __restrict__ V, u16* __restrict__ Vt){
  __shared__ __align__(16) u16 ts[64][72];
  int t=threadIdx.x, z=blockIdx.y, n0=blockIdx.x*64;
  int b=z>>4, hh=z&15;
  {
    int row=t>>2, c16=(t&3)*16;
    const u16* src = V + ((long)b*N_ + n0+row)*D_ + hh*DH_ + c16;
    *(uint4*)&ts[row][c16]   = *(const uint4*)src;
    *(uint4*)&ts[row][c16+8] = *(const uint4*)(src+8);
  }
  __syncthreads();
  {
    int d=t>>2, nc=(t&3)*16;
    union { u16 u[16]; uint4 q[2]; } tmp;
    #pragma unroll
    for (int j=0;j<16;j++) tmp.u[j]=ts[nc+j][d];
    u16* dst = Vt + (long)z*DH_*N_ + (long)d*N_ + n0+nc;
    *(uint4*)dst = tmp.q[0];
    *(uint4*)(dst+8) = tmp.q[1];
  }
}

__global__ void sinit_k(unsigned* sk){ int t=threadIdx.x; if (t<BH_) sk[t]=0u; }

// ---------------- dd kernel: per-head dd = X_head @ proj^T, K=64 ----------------
// MODE 0: global max -> atomicMax key    MODE 1: kp_t[zl][m][n] (transposed)
// MODE 2: qp[zl][n][m] with per-row max
template<int MODE>
__global__ __launch_bounds__(256) void dd_k(
    const u16* __restrict__ X, const u16* __restrict__ P,
    const float* __restrict__ dg, unsigned* __restrict__ sk,
    u16* __restrict__ out, int zoff)
{
  __shared__ __align__(16) char smem[46080];
  u16*   Ps = (u16*)smem;               // swizzled proj 256x64 (32KB)
  u16*   Xs = (u16*)(smem + 36864);     // swizzled X tile 64x64 (8KB)
  float* rm = (float*)(smem + 45056);   // row/max scratch (1KB)
  u16*   Tr = (u16*)smem;               // [256][72] transpose buf (MODE 1)
  int t=threadIdx.x;
  int zl=blockIdx.y, zg=zl+zoff, n0=blockIdx.x*64;
  int b=zg>>4, hh=zg&15;

  #pragma unroll
  for (int i=0;i<8;i++){                // proj: 256 rows x 64
    int c=t+i*256, row=c>>3, c8=c&7;
    uint4 dv = *(const uint4*)(P + row*64 + c8*8);
    *(uint4*)((char*)Ps + (row<<7) + ((c8<<4)^((row&7)<<4))) = dv;
  }
  #pragma unroll
  for (int i=0;i<2;i++){                // X tile: 64 rows x 64
    int c=t+i*256, row=c>>3, c8=c&7;
    uint4 dv = *(const uint4*)(X + ((long)b*N_ + n0+row)*D_ + hh*DH_ + c8*8);
    *(uint4*)((char*)Xs + (row<<7) + ((c8<<4)^((row&7)<<4))) = dv;
  }
  __syncthreads();

  int w=t>>6, lane=t&63, lr=lane&15, lg=lane>>4;
  f32x4 acc[4][4];
  #pragma unroll
  for (int mi=0;mi<4;mi++)
    #pragma unroll
    for (int ni=0;ni<4;ni++) acc[mi][ni]=(f32x4){0.f,0.f,0.f,0.f};

  #pragma unroll
  for (int ks=0;ks<2;ks++){
    bf16x8 aF[4], bF[4];
    #pragma unroll
    for (int mi=0;mi<4;mi++){
      int row=mi*16+lr;
      aF[mi]=*(const bf16x8*)((const char*)Xs + (row<<7) + ((((ks<<2)+lg)<<4)^((row&7)<<4)));
    }
    #pragma unroll
    for (int ni=0;ni<4;ni++){
      int row=w*64+ni*16+lr;
      bF[ni]=*(const bf16x8*)((const char*)Ps + (row<<7) + ((((ks<<2)+lg)<<4)^((row&7)<<4)));
    }
    #pragma unroll
    for (int mi=0;mi<4;mi++)
      #pragma unroll
      for (int ni=0;ni<4;ni++)
        acc[mi][ni]=__builtin_amdgcn_mfma_f32_16x16x32_bf16(aF[mi],bF[ni],acc[mi][ni],0,0,0);
  }

  const float SN = 0.35355339059327373f;   // 64^-0.25

  if (MODE==0){
    float mx = acc[0][0][0];
    #pragma unroll
    for (int mi=0;mi<4;mi++)
      #pragma unroll
      for (int ni=0;ni<4;ni++)
        #pragma unroll
        for (int r=0;r<4;r++) mx=fmaxf(mx,acc[mi][ni][r]);
    #pragma unroll
    for (int m=1;m<64;m<<=1) mx = fmaxf(mx, __shfl_xor(mx,m));
    if (lane==0) rm[w]=mx;
    __syncthreads();
    if (t==0) atomicMax(sk+zg, fkey(SN*fmaxf(fmaxf(rm[0],rm[1]),fmaxf(rm[2],rm[3]))));
  }
  else if (MODE==1){
    float stab = fdec(sk[zg]);
    const float* dgz = dg + (long)zl*N_ + n0;
    __syncthreads();                        // all waves done reading Ps before Tr overwrite
    #pragma unroll
    for (int mi=0;mi<4;mi++)
      #pragma unroll
      for (int ni=0;ni<4;ni++){
        int col = w*64 + ni*16 + lr;
        #pragma unroll
        for (int r=0;r<4;r++){
          int rw = mi*16 + lg*4 + r;
          float kp = 0.0625f*(expf(SN*acc[mi][ni][r] - dgz[rw] - stab) + 1e-4f);
          Tr[col*72 + rw] = f2b(kp);
        }
      }
    __syncthreads();
    const uint4* src = (const uint4*)(Tr + t*72);
    uint4* dst = (uint4*)(out + (long)zl*((long)M_*N_) + (long)t*N_ + n0);
    #pragma unroll
    for (int j=0;j<8;j++) dst[j] = src[j];
  }
  else {
    float rmx[4][4];
    #pragma unroll
    for (int mi=0;mi<4;mi++)
      #pragma unroll
      for (int r=0;r<4;r++){
        float v = acc[mi][0][r];
        #pragma unroll
        for (int ni=1;ni<4;ni++) v=fmaxf(v, acc[mi][ni][r]);
        #pragma unroll
        for (int m=1;m<16;m<<=1) v = fmaxf(v, __shfl_xor(v,m));
        rmx[mi][r]=v;
      }
    if (lr==0){
      #pragma unroll
      for (int mi=0;mi<4;mi++)
        #pragma unroll
        for (int r=0;r<4;r++) rm[w*64 + mi*16 + lg*4 + r] = rmx[mi][r];
    }
    __syncthreads();
    const float* dgz = dg + (long)zl*N_ + n0;
    #pragma unroll
    for (int mi=0;mi<4;mi++)
      #pragma unroll
      for (int r=0;r<4;r++){
        int rw = mi*16+lg*4+r;
        float st = fmaxf(fmaxf(rm[rw],rm[64+rw]),fmaxf(rm[128+rw],rm[192+rw]));
        float dgv = dgz[rw];
        #pragma unroll
        for (int ni=0;ni<4;ni++){
          int col = w*64+ni*16+lr;
          float qpv = 0.0625f*(expf(SN*acc[mi][ni][r] - dgv - SN*st) + 1e-4f);
          out[(long)zl*((long)N_*M_) + (long)(n0+rw)*M_ + col] = f2b(qpv);
        }
      }
  }
}

// ---------------- ksum[m-row r] = sum_n kp_t[r][n] (chunk-local) ----------------
__global__ __launch_bounds__(256) void ksum_k(const u16* __restrict__ kpt, float* __restrict__ ks){
  int t=threadIdx.x, w=t>>6, lane=t&63;
  long r=(long)blockIdx.x*4+w;           // r = zl*M_ + m
  const u16* row = kpt + r*N_;
  float s=0.f;
  #pragma unroll
  for (int j=0;j<4;j++){
    uint4 q = *(const uint4*)(row + lane*8 + j*512);
    const u16* p=(const u16*)&q;
    #pragma unroll
    for (int e=0;e<8;e++) s += b2f(p[e]);
  }
  #pragma unroll
  for (int m=1;m<64;m<<=1) s += __shfl_xor(s,m);
  if (lane==0) ks[r]=s;
}

// ---------------- d_inv (chunk-local) ----------------
__global__ __launch_bounds__(256) void dinv_k(const u16* __restrict__ qp,
    const float* __restrict__ ks, float* __restrict__ di){
  int t=threadIdx.x, w=t>>6, lane=t&63;
  long r=(long)blockIdx.x*4+w;           // r = zl*N_ + n
  long z = r>>11;
  const u16* row = qp + r*M_;
  const float* kz = ks + z*M_;
  float s=0.f;
  uint2 q = *(const uint2*)(row + lane*4);
  const u16* p=(const u16*)&q;
  #pragma unroll
  for (int e=0;e<4;e++) s += b2f(p[e])*kz[lane*4+e];
  #pragma unroll
  for (int m=1;m<64;m<<=1) s+=__shfl_xor(s,m);
  if (lane==0) di[r]=1.0f/s;
}

// ---------------- ctx split-K reduce ----------------
__global__ __launch_bounds__(256) void ctxred_k(const float* __restrict__ p, u16* __restrict__ c){
  long i = (long)blockIdx.x*256 + threadIdx.x;   // [0, CH*DH*M)
  long z = i >> 14, rem = i & 16383;
  float s = 0.f;
  #pragma unroll
  for (int j=0;j<SPLIT_;j++) s += p[((z<<2)+j)*16384 + rem];
  c[i] = f2b(s);
}

// ---------------- generic bf16 MFMA GEMM: C = A(MxK) * W(NxK)^T ----------------
// A: per-lane direct global->VGPR fragments (16B contiguous), double-buffered regs.
// W: double-buffered LDS via global_load_lds; linear dest + pre-swizzled global
//    source column ((lane&7)^(lane>>3)) so XOR read is conflict-free (rule 21).
// Pipeline: stage W[t+1]+load A[t+1] -> compute(W[t],A[t]) -> barrier (drains both).
// EPI 0: bf16 = acc+bias   1: f32 resid += acc+bias   2: bf16 = gelu(acc+bias)
// EPI 3: bf16 = acc        4: bf16 = acc * dinv[z][row]
// EPI 5: split-K partials  6: fused QKV: route by col>>10 into 3 contiguous buffers
template<int BM,int BN,int WR,int WC,int EPI,bool XS>
__global__ __launch_bounds__(256) void gemm_k(
    const u16* __restrict__ A, int lda, long sA,
    const u16* __restrict__ W, int ldw, long sW,
    const float* __restrict__ bias,
    void* __restrict__ Cv, int ldc, long sCb, long sCh,
    const float* __restrict__ dinv, int K)
{
  static_assert(WR*WC==4, "4 waves");
  constexpr int WM=BM/WR, WN=BN/WC, MI=WM/16, NI=WN/16;
  __shared__ __align__(16) u16 Ws0[BN*64];
  __shared__ __align__(16) u16 Ws1[BN*64];
  int t=threadIdx.x, z=blockIdx.z;
  int bx, by;
  if (XS){
    unsigned gx=gridDim.x, flat=blockIdx.y*gx+blockIdx.x;
    unsigned cpx=(gx*gridDim.y)>>3;
    unsigned s=(flat&7)*cpx + (flat>>3);
    bx = s % gx; by = s / gx;
  } else { bx = blockIdx.x; by = blockIdx.y; }
  int bxn = (EPI==5) ? 0 : bx;
  int kb0 = (EPI==5) ? bx*K : 0;
  int w=t>>6, lane=t&63, lr=lane&15, lg=lane>>4;
  int wr=w/WC, wc=w%WC;
  const u16* Wb = W + (long)z*sW + (long)bxn*BN*ldw;
  const u16* At = A + (long)z*sA + ((long)by*BM + wr*WM + lr)*lda;  // thread A row base
  int srow=lane>>3;
  int swcol=((lane&7)^srow)*8;          // swizzled global source col (halfwords)

  auto stageW=[&](u16* Ls, int k0){
    #pragma unroll
    for (int i=0;i<BN/32;i++){
      int rb=w*(BN/4)+i*8;
      gload16(Wb + (long)(rb+srow)*ldw + k0 + swcol, Ls + rb*64);
    }
  };
  bf16x8 aA[MI][2], aB[MI][2];
  auto loadA=[&](bf16x8 (&aR)[MI][2], int k0){
    #pragma unroll
    for (int mi=0;mi<MI;mi++)
      #pragma unroll
      for (int ks=0;ks<2;ks++)
        aR[mi][ks]=*(const bf16x8*)(At + (long)mi*16*lda + k0 + ks*32 + lg*8);
  };
  f32x4 acc[MI][NI];
  #pragma unroll
  for (int mi=0;mi<MI;mi++)
    #pragma unroll
    for(int ni=0;ni<NI;ni++) acc[mi][ni]=(f32x4){0.f,0.f,0.f,0.f};
  auto compute=[&](const u16* Ls, bf16x8 (&aR)[MI][2]){
    #pragma unroll
    for (int ks=0;ks<2;ks++){
      bf16x8 bF[NI];
      #pragma unroll
      for (int ni=0;ni<NI;ni++){
        int row=wc*WN+ni*16+lr;
        bF[ni]=*(const bf16x8*)((const char*)Ls + (row<<7) + ((((ks<<2)+lg)<<4)^((row&7)<<4)));
      }
      #pragma unroll
      for (int mi=0;mi<MI;mi++)
        #pragma unroll
        for (int ni=0;ni<NI;ni++)
          acc[mi][ni]=__builtin_amdgcn_mfma_f32_16x16x32_bf16(aR[mi][ks],bF[ni],acc[mi][ni],0,0,0);
    }
  };

  stageW(Ws0, kb0); loadA(aA, kb0);
  __syncthreads();
  int nT = K/128;
  for (int it=0; it<nT; ++it){
    int k0 = kb0 + it*128;
    stageW(Ws1, k0+64); loadA(aB, k0+64);
    compute(Ws0, aA);
    __syncthreads();
    if (it+1<nT){ stageW(Ws0, k0+128); loadA(aA, k0+128); }
    compute(Ws1, aB);
    __syncthreads();
  }

  long coff = (long)(z>>4)*sCb + (long)(z&15)*sCh;
  #pragma unroll
  for (int mi=0;mi<MI;mi++){
    #pragma unroll
    for (int ni=0;ni<NI;ni++){
      int col = bxn*BN + wc*WN + ni*16 + lr;
      float bv = (EPI<=2 || EPI==6) ? bias[col] : 0.0f;
      #pragma unroll
      for (int r=0;r<4;r++){
        int row = by*BM + wr*WM + mi*16 + lg*4 + r;
        float v = acc[mi][ni][r];
        if (EPI==0){
          ((u16*)Cv)[coff + (long)row*ldc + col] = f2b(v+bv);
        } else if (EPI==1){
          ((float*)Cv)[coff + (long)row*ldc + col] += v+bv;
        } else if (EPI==2){
          float u=v+bv;
          ((u16*)Cv)[coff + (long)row*ldc + col] = f2b(0.5f*u*(1.0f+erff(u*0.70710678118654752f)));
        } else if (EPI==3){
          ((u16*)Cv)[coff + (long)row*ldc + col] = f2b(v);
        } else if (EPI==4){
          ((u16*)Cv)[coff + (long)row*ldc + col] = f2b(v*dinv[(long)z*N_ + row]);
        } else if (EPI==5){
          ((float*)Cv)[((long)z*gridDim.x + bx)*((long)BM*ldc) + (long)row*ldc + col] = v;
        } else {
          int seg = col>>10, c = col&1023;
          ((u16*)Cv)[(long)seg*((long)ROWS_*D_) + (long)row*D_ + c] = f2b(v+bv);
        }
      }
    }
  }
}

// =================================================================
struct WS {
  u16 *wbuf, *pjb, *hb, *qb, *kb, *pbuf, *sh16, *ctxT;
  float *fbias, *part, *dgq, *dgkdnv, *ksm; unsigned* sky;
  size_t total;
};
static WS plan_ws(char* base, int CH){
  WS w; size_t off=0;
  auto al=[&](size_t b)->char*{ char* p=base+off; off=(off+b+255)&~(size_t)255; return p; };
  const size_t TB=(size_t)ROWS_*D_*2;
  w.wbuf=(u16*)al(6ull*D_*D_*2);
  w.pjb =(u16*)al((size_t)L_*M_*DH_*2);
  w.fbias=(float*)al(3*D_*4);
  w.hb  =(u16*)al(TB);
  // qb, kb, pbuf MUST be contiguous (fused-QKV epilogue: seg*ROWS_*D_)
  w.qb  =(u16*)al(TB);
  w.kb  =(u16*)al(TB);
  size_t pb=(size_t)CH*M_*N_*2; if (pb<TB) pb=TB;   // also hosts vb (seg 2)
  w.pbuf=(u16*)al(pb);
  w.sh16=(u16*)al(TB);
  w.part=(float*)al((size_t)CH*SPLIT_*DH_*M_*4);
  w.ctxT=(u16*)al((size_t)BH_*DH_*M_*2);
  w.dgq =(float*)al((size_t)BH_*N_*4);
  w.dgkdnv=(float*)al((size_t)BH_*N_*4);
  w.ksm =(float*)al((size_t)BH_*M_*4);
  w.sky =(unsigned*)al(BH_*4);
  w.total=off;
  return w;
}

extern "C" void kernel_launch(void* const* d_in, const int* in_sizes, int n_in,
                              void* d_out, int out_size, void* d_ws, size_t ws_size,
                              hipStream_t stream)
{
  const float* x    = (const float*)d_in[0];
  const float* proj = (const float*)d_in[1];
  const float* ln1g = (const float*)d_in[2];
  const float* ln1b = (const float*)d_in[3];
  const float* Wq   = (const float*)d_in[4];
  const float* bq   = (const float*)d_in[5];
  const float* Wk   = (const float*)d_in[6];
  const float* bk   = (const float*)d_in[7];
  const float* Wv   = (const float*)d_in[8];
  const float* bv   = (const float*)d_in[9];
  const float* Wo   = (const float*)d_in[10];
  const float* bo   = (const float*)d_in[11];
  const float* ln2g = (const float*)d_in[12];
  const float* ln2b = (const float*)d_in[13];
  const float* W1   = (const float*)d_in[14];
  const float* b1   = (const float*)d_in[15];
  const float* W2   = (const float*)d_in[16];
  const float* b2   = (const float*)d_in[17];

  char* base=(char*)d_ws;
  int CH=64;
  WS w = plan_ws(base, 64);
  if (w.total > ws_size){ CH=16; w = plan_ws(base, 16); }
  if (w.total > ws_size){
    fillf_k<<<(out_size+255)/256,256,0,stream>>>((float*)d_out,(long)out_size,(float)(ws_size>>20));
    return;
  }
  const int NCH = BH_/CH;

  u16* vb = w.pbuf;     // alias: V output (seg 2 of fused QKV), dead before kp_t written
  u16* vt = w.sh16;     // alias: v_t, dead before tm written
  u16* at = w.hb;       // alias: attn out, hb dead between QKV-GEMM and ln2
  u16* tm = w.sh16;     // alias: FFN intermediate
  float* dnv = w.dgkdnv;// alias: dgk dead before dinv written

  wcvt_k<<<(L_*M_*DH_/4+255)/256,256,0,stream>>>(proj,w.pjb,(long)L_*M_*DH_);
  hipMemcpyAsync(d_out, x, (size_t)ROWS_*D_*4, hipMemcpyDeviceToDevice, stream);
  float* Xc = (float*)d_out;

  const long wn = (long)D_*D_;
  const int wg = (int)(wn/4/256);
  dim3 gBig(D_/128, ROWS_/128, 1);
  dim3 gQKV(3*D_/128, ROWS_/128, 1);

  for (int l=0;l<L_;l++){
    u16* wqkv=w.wbuf;         // wq|wk|wv contiguous = fused 3072x1024
    u16* wo=w.wbuf+3*wn;      u16* w1=w.wbuf+4*wn; u16* w2=w.wbuf+5*wn;
    wcvt_k<<<wg,256,0,stream>>>(Wq+(size_t)l*wn,w.wbuf,wn);
    wcvt_k<<<wg,256,0,stream>>>(Wk+(size_t)l*wn,w.wbuf+wn,wn);
    wcvt_k<<<wg,256,0,stream>>>(Wv+(size_t)l*wn,w.wbuf+2*wn,wn);
    wcvt_k<<<wg,256,0,stream>>>(Wo+(size_t)l*wn,wo,wn);
    wcvt_k<<<wg,256,0,stream>>>(W1+(size_t)l*wn,w1,wn);
    wcvt_k<<<wg,256,0,stream>>>(W2+(size_t)l*wn,w2,wn);
    hipMemcpyAsync(w.fbias,       bq+(size_t)l*D_, D_*4, hipMemcpyDeviceToDevice, stream);
    hipMemcpyAsync(w.fbias+D_,    bk+(size_t)l*D_, D_*4, hipMemcpyDeviceToDevice, stream);
    hipMemcpyAsync(w.fbias+2*D_,  bv+(size_t)l*D_, D_*4, hipMemcpyDeviceToDevice, stream);
    const u16* pj = w.pjb + (size_t)l*M_*DH_;

    ln_k<<<ROWS_,256,0,stream>>>(Xc, ln1g+(size_t)l*D_, ln1b+(size_t)l*D_, w.hb);
    // fused QKV: C routed by col>>10 into qb|kb|pbuf (contiguous)
    gemm_k<128,128,2,2,6,true><<<gQKV,256,0,stream>>>(w.hb,D_,0, wqkv,D_,0, w.fbias, w.qb,D_,0,0,nullptr,D_);
    vt_k<<<dim3(N_/64,BH_),256,0,stream>>>(vb, vt);
    diagk_k<<<BH_*N_/4,256,0,stream>>>(w.qb, w.dgq);
    diagk_k<<<BH_*N_/4,256,0,stream>>>(w.kb, w.dgkdnv);
    sinit_k<<<1,64,0,stream>>>(w.sky);

    for (int ch=0; ch<NCH; ch++){
      int zoff = ch*CH;
      u16* kq = w.pbuf;   // chunk-local kp_t then qp
      dd_k<0><<<dim3(N_/64,CH),256,0,stream>>>(w.kb,pj,nullptr,w.sky,nullptr,zoff);
      dd_k<1><<<dim3(N_/64,CH),256,0,stream>>>(w.kb,pj,w.dgkdnv+(long)zoff*N_,w.sky,kq,zoff);
      ksum_k<<<CH*M_/4,256,0,stream>>>(kq, w.ksm+(long)zoff*M_);
      gemm_k<64,256,1,4,5,false><<<dim3(SPLIT_,1,CH),256,0,stream>>>(
          vt+(long)zoff*DH_*N_, N_, (long)DH_*N_,
          kq, N_, (long)M_*N_, nullptr,
          w.part, M_, 0,0, nullptr, N_/SPLIT_);
      ctxred_k<<<CH*DH_*M_/256,256,0,stream>>>(w.part, w.ctxT+(long)zoff*DH_*M_);
      dd_k<2><<<dim3(N_/64,CH),256,0,stream>>>(w.qb,pj,w.dgq+(long)zoff*N_,w.sky,kq,zoff);
      dinv_k<<<CH*N_/4,256,0,stream>>>(kq, w.ksm+(long)zoff*M_, dnv+(long)zoff*N_);
      gemm_k<128,64,2,2,4,false><<<dim3(1,N_/128,CH),256,0,stream>>>(
          kq, M_, (long)N_*M_,
          w.ctxT+(long)zoff*DH_*M_, M_, (long)DH_*M_, nullptr,
          at+(long)(zoff>>4)*N_*D_, D_, (long)N_*D_, (long)DH_, dnv+(long)zoff*N_, M_);
    }

    gemm_k<128,128,2,2,1,true><<<gBig,256,0,stream>>>(at,D_,0, wo,D_,0, bo+(size_t)l*D_, Xc,D_,0,0,nullptr,D_);
    ln_k<<<ROWS_,256,0,stream>>>(Xc, ln2g+(size_t)l*D_, ln2b+(size_t)l*D_, w.hb);
    gemm_k<128,128,2,2,2,true><<<gBig,256,0,stream>>>(w.hb,D_,0, w1,D_,0, b1+(size_t)l*D_, tm,D_,0,0,nullptr,D_);
    gemm_k<128,128,2,2,1,true><<<gBig,256,0,stream>>>(tm,D_,0, w2,D_,0, b2+(size_t)l*D_, Xc,D_,0,0,nullptr,D_);
  }
}

// Round 5
// 1603.406 us; speedup vs baseline: 1.3378x; 1.3378x over previous
//
#include <hip/hip_runtime.h>

#define B_    4
#define N_    2048
#define D_    1024
#define L_    4
#define M_    256
#define DH_   64
#define H_    16
#define BH_   64      // B_*H_
#define ROWS_ 8192    // B_*N_
#define SPLIT_ 4      // ctx GEMM k-split

typedef __bf16 bf16x8 __attribute__((ext_vector_type(8)));
typedef float  f32x4  __attribute__((ext_vector_type(4)));
typedef unsigned short u16;

__device__ __forceinline__ u16 f2b(float f){
  unsigned u = __float_as_uint(f);
  u += 0x7FFFu + ((u >> 16) & 1u);          // RNE
  return (u16)(u >> 16);
}
__device__ __forceinline__ float b2f(u16 h){ return __uint_as_float(((unsigned)h) << 16); }
__device__ __forceinline__ unsigned fkey(float x){
  unsigned u = __float_as_uint(x);
  return (u & 0x80000000u) ? ~u : (u | 0x80000000u);
}
__device__ __forceinline__ float fdec(unsigned k){
  unsigned u = (k & 0x80000000u) ? (k ^ 0x80000000u) : ~k;
  return __uint_as_float(u);
}

// global -> LDS direct, 16B per lane. LDS dest is wave-uniform base + lane*16.
__device__ __forceinline__ void gload16(const u16* g, u16* l){
  __builtin_amdgcn_global_load_lds(
      (const __attribute__((address_space(1))) void*)g,
      (__attribute__((address_space(3))) void*)l, 16, 0, 0);
}

// ---------------- fp32 -> bf16 convert ----------------
__global__ __launch_bounds__(256) void wcvt_k(const float* __restrict__ s, u16* __restrict__ d, long n){
  long i = ((long)blockIdx.x*256 + threadIdx.x)*4;
  if (i+3 < n){
    float4 v = *(const float4*)(s+i);
    d[i]=f2b(v.x); d[i+1]=f2b(v.y); d[i+2]=f2b(v.z); d[i+3]=f2b(v.w);
  } else {
    for(long j=i;j<n;j++) d[j]=f2b(s[j]);
  }
}

// ---------------- diagnostic fill ----------------
__global__ void fillf_k(float* o, long n, float v){
  long i=(long)blockIdx.x*256+threadIdx.x; if(i<n) o[i]=v;
}

// ---------------- LayerNorm: fp32 row -> bf16 row ----------------
__global__ __launch_bounds__(256) void ln_k(const float* __restrict__ x,
    const float* __restrict__ g, const float* __restrict__ bt, u16* __restrict__ h){
  int row = blockIdx.x, t = threadIdx.x;
  const float* xr = x + (long)row*D_;
  float4 v = *(const float4*)(xr + t*4);
  float s  = v.x+v.y+v.z+v.w;
  float ss = v.x*v.x+v.y*v.y+v.z*v.z+v.w*v.w;
  #pragma unroll
  for (int m=1;m<64;m<<=1){ s += __shfl_xor(s,m); ss += __shfl_xor(ss,m); }
  __shared__ float ps[4][2];
  int w=t>>6;
  if ((t&63)==0){ ps[w][0]=s; ps[w][1]=ss; }
  __syncthreads();
  s  = ps[0][0]+ps[1][0]+ps[2][0]+ps[3][0];
  ss = ps[0][1]+ps[1][1]+ps[2][1]+ps[3][1];
  float mean = s*(1.0f/D_);
  float rs = rsqrtf(ss*(1.0f/D_) - mean*mean + 1e-5f);
  int c=t*4;
  u16* hr = h + (long)row*D_;
  hr[c+0]=f2b((v.x-mean)*rs*g[c+0]+bt[c+0]);
  hr[c+1]=f2b((v.y-mean)*rs*g[c+1]+bt[c+1]);
  hr[c+2]=f2b((v.z-mean)*rs*g[c+2]+bt[c+2]);
  hr[c+3]=f2b((v.w-mean)*rs*g[c+3]+bt[c+3]);
}

// ---------------- diag[z][n] = sum_d x^2 / 16 ----------------
__global__ __launch_bounds__(256) void diagk_k(const u16* __restrict__ X, float* __restrict__ dg){
  int t=threadIdx.x, w=t>>6, lane=t&63;
  long r=(long)blockIdx.x*4+w;           // r = z*N_ + n
  int z=(int)(r>>11), n=(int)(r&2047);
  int b=z>>4, hh=z&15;
  float v=b2f(X[((long)b*N_+n)*D_ + hh*DH_ + lane]);
  float sq=v*v;
  #pragma unroll
  for (int m=1;m<64;m<<=1) sq += __shfl_xor(sq,m);
  if (lane==0) dg[r]=sq*0.0625f;
}

// ---------------- v (B,N,H,dh) -> v_t [z][d][n] ----------------
__global__ __launch_bounds__(256) void vt_k(const u16* __restrict__ V, u16* __restrict__ Vt){
  __shared__ __align__(16) u16 ts[64][72];
  int t=threadIdx.x, z=blockIdx.y, n0=blockIdx.x*64;
  int b=z>>4, hh=z&15;
  {
    int row=t>>2, c16=(t&3)*16;
    const u16* src = V + ((long)b*N_ + n0+row)*D_ + hh*DH_ + c16;
    *(uint4*)&ts[row][c16]   = *(const uint4*)src;
    *(uint4*)&ts[row][c16+8] = *(const uint4*)(src+8);
  }
  __syncthreads();
  {
    int d=t>>2, nc=(t&3)*16;
    union { u16 u[16]; uint4 q[2]; } tmp;
    #pragma unroll
    for (int j=0;j<16;j++) tmp.u[j]=ts[nc+j][d];
    u16* dst = Vt + (long)z*DH_*N_ + (long)d*N_ + n0+nc;
    *(uint4*)dst = tmp.q[0];
    *(uint4*)(dst+8) = tmp.q[1];
  }
}

__global__ void sinit_k(unsigned* sk){ int t=threadIdx.x; if (t<BH_) sk[t]=0u; }

// ---------------- dd kernel: per-head dd = X_head @ proj^T, K=64 ----------------
// MODE 0: global max -> atomicMax key    MODE 1: kp_t[zl][m][n] (transposed)
// MODE 2: qp[zl][n][m] with per-row max
template<int MODE>
__global__ __launch_bounds__(256) void dd_k(
    const u16* __restrict__ X, const u16* __restrict__ P,
    const float* __restrict__ dg, unsigned* __restrict__ sk,
    u16* __restrict__ out, int zoff)
{
  __shared__ __align__(16) char smem[46080];
  u16*   Ps = (u16*)smem;               // swizzled proj 256x64 (32KB)
  u16*   Xs = (u16*)(smem + 36864);     // swizzled X tile 64x64 (8KB)
  float* rm = (float*)(smem + 45056);   // row/max scratch (1KB)
  u16*   Tr = (u16*)smem;               // [256][72] transpose buf (MODE 1)
  int t=threadIdx.x;
  int zl=blockIdx.y, zg=zl+zoff, n0=blockIdx.x*64;
  int b=zg>>4, hh=zg&15;

  #pragma unroll
  for (int i=0;i<8;i++){                // proj: 256 rows x 64
    int c=t+i*256, row=c>>3, c8=c&7;
    uint4 dv = *(const uint4*)(P + row*64 + c8*8);
    *(uint4*)((char*)Ps + (row<<7) + ((c8<<4)^((row&7)<<4))) = dv;
  }
  #pragma unroll
  for (int i=0;i<2;i++){                // X tile: 64 rows x 64
    int c=t+i*256, row=c>>3, c8=c&7;
    uint4 dv = *(const uint4*)(X + ((long)b*N_ + n0+row)*D_ + hh*DH_ + c8*8);
    *(uint4*)((char*)Xs + (row<<7) + ((c8<<4)^((row&7)<<4))) = dv;
  }
  __syncthreads();

  int w=t>>6, lane=t&63, lr=lane&15, lg=lane>>4;
  f32x4 acc[4][4];
  #pragma unroll
  for (int mi=0;mi<4;mi++)
    #pragma unroll
    for (int ni=0;ni<4;ni++) acc[mi][ni]=(f32x4){0.f,0.f,0.f,0.f};

  #pragma unroll
  for (int ks=0;ks<2;ks++){
    bf16x8 aF[4], bF[4];
    #pragma unroll
    for (int mi=0;mi<4;mi++){
      int row=mi*16+lr;
      aF[mi]=*(const bf16x8*)((const char*)Xs + (row<<7) + ((((ks<<2)+lg)<<4)^((row&7)<<4)));
    }
    #pragma unroll
    for (int ni=0;ni<4;ni++){
      int row=w*64+ni*16+lr;
      bF[ni]=*(const bf16x8*)((const char*)Ps + (row<<7) + ((((ks<<2)+lg)<<4)^((row&7)<<4)));
    }
    #pragma unroll
    for (int mi=0;mi<4;mi++)
      #pragma unroll
      for (int ni=0;ni<4;ni++)
        acc[mi][ni]=__builtin_amdgcn_mfma_f32_16x16x32_bf16(aF[mi],bF[ni],acc[mi][ni],0,0,0);
  }

  const float SN = 0.35355339059327373f;   // 64^-0.25

  if (MODE==0){
    float mx = acc[0][0][0];
    #pragma unroll
    for (int mi=0;mi<4;mi++)
      #pragma unroll
      for (int ni=0;ni<4;ni++)
        #pragma unroll
        for (int r=0;r<4;r++) mx=fmaxf(mx,acc[mi][ni][r]);
    #pragma unroll
    for (int m=1;m<64;m<<=1) mx = fmaxf(mx, __shfl_xor(mx,m));
    if (lane==0) rm[w]=mx;
    __syncthreads();
    if (t==0) atomicMax(sk+zg, fkey(SN*fmaxf(fmaxf(rm[0],rm[1]),fmaxf(rm[2],rm[3]))));
  }
  else if (MODE==1){
    float stab = fdec(sk[zg]);
    const float* dgz = dg + (long)zl*N_ + n0;
    __syncthreads();                        // all waves done reading Ps before Tr overwrite
    #pragma unroll
    for (int mi=0;mi<4;mi++)
      #pragma unroll
      for (int ni=0;ni<4;ni++){
        int col = w*64 + ni*16 + lr;
        #pragma unroll
        for (int r=0;r<4;r++){
          int rw = mi*16 + lg*4 + r;
          float kp = 0.0625f*(expf(SN*acc[mi][ni][r] - dgz[rw] - stab) + 1e-4f);
          Tr[col*72 + rw] = f2b(kp);
        }
      }
    __syncthreads();
    const uint4* src = (const uint4*)(Tr + t*72);
    uint4* dst = (uint4*)(out + (long)zl*((long)M_*N_) + (long)t*N_ + n0);
    #pragma unroll
    for (int j=0;j<8;j++) dst[j] = src[j];
  }
  else {
    float rmx[4][4];
    #pragma unroll
    for (int mi=0;mi<4;mi++)
      #pragma unroll
      for (int r=0;r<4;r++){
        float v = acc[mi][0][r];
        #pragma unroll
        for (int ni=1;ni<4;ni++) v=fmaxf(v, acc[mi][ni][r]);
        #pragma unroll
        for (int m=1;m<16;m<<=1) v = fmaxf(v, __shfl_xor(v,m));
        rmx[mi][r]=v;
      }
    if (lr==0){
      #pragma unroll
      for (int mi=0;mi<4;mi++)
        #pragma unroll
        for (int r=0;r<4;r++) rm[w*64 + mi*16 + lg*4 + r] = rmx[mi][r];
    }
    __syncthreads();
    const float* dgz = dg + (long)zl*N_ + n0;
    #pragma unroll
    for (int mi=0;mi<4;mi++)
      #pragma unroll
      for (int r=0;r<4;r++){
        int rw = mi*16+lg*4+r;
        float st = fmaxf(fmaxf(rm[rw],rm[64+rw]),fmaxf(rm[128+rw],rm[192+rw]));
        float dgv = dgz[rw];
        #pragma unroll
        for (int ni=0;ni<4;ni++){
          int col = w*64+ni*16+lr;
          float qpv = 0.0625f*(expf(SN*acc[mi][ni][r] - dgv - SN*st) + 1e-4f);
          out[(long)zl*((long)N_*M_) + (long)(n0+rw)*M_ + col] = f2b(qpv);
        }
      }
  }
}

// ---------------- ksum[m-row r] = sum_n kp_t[r][n] (chunk-local) ----------------
__global__ __launch_bounds__(256) void ksum_k(const u16* __restrict__ kpt, float* __restrict__ ks){
  int t=threadIdx.x, w=t>>6, lane=t&63;
  long r=(long)blockIdx.x*4+w;           // r = zl*M_ + m
  const u16* row = kpt + r*N_;
  float s=0.f;
  #pragma unroll
  for (int j=0;j<4;j++){
    uint4 q = *(const uint4*)(row + lane*8 + j*512);
    const u16* p=(const u16*)&q;
    #pragma unroll
    for (int e=0;e<8;e++) s += b2f(p[e]);
  }
  #pragma unroll
  for (int m=1;m<64;m<<=1) s += __shfl_xor(s,m);
  if (lane==0) ks[r]=s;
}

// ---------------- d_inv (chunk-local) ----------------
__global__ __launch_bounds__(256) void dinv_k(const u16* __restrict__ qp,
    const float* __restrict__ ks, float* __restrict__ di){
  int t=threadIdx.x, w=t>>6, lane=t&63;
  long r=(long)blockIdx.x*4+w;           // r = zl*N_ + n
  long z = r>>11;
  const u16* row = qp + r*M_;
  const float* kz = ks + z*M_;
  float s=0.f;
  uint2 q = *(const uint2*)(row + lane*4);
  const u16* p=(const u16*)&q;
  #pragma unroll
  for (int e=0;e<4;e++) s += b2f(p[e])*kz[lane*4+e];
  #pragma unroll
  for (int m=1;m<64;m<<=1) s+=__shfl_xor(s,m);
  if (lane==0) di[r]=1.0f/s;
}

// ---------------- ctx split-K reduce ----------------
__global__ __launch_bounds__(256) void ctxred_k(const float* __restrict__ p, u16* __restrict__ c){
  long i = (long)blockIdx.x*256 + threadIdx.x;   // [0, CH*DH*M)
  long z = i >> 14, rem = i & 16383;
  float s = 0.f;
  #pragma unroll
  for (int j=0;j<SPLIT_;j++) s += p[((z<<2)+j)*16384 + rem];
  c[i] = f2b(s);
}

// ---------------- generic bf16 MFMA GEMM: C = A(MxK) * W(NxK)^T ----------------
// Both operands staged via global_load_lds (coalesced, linear LDS dest) with
// pre-swizzled GLOBAL source column ((lane&7)^(lane>>3)); reads apply the same
// XOR -> 2-way bank aliasing = free (m136). Simple m97 2-barrier loop; grid
// sized for >=4 blocks/CU via 64x128 tiles.
// EPI 0: bf16 = acc+bias   1: f32 resid += acc+bias   2: bf16 = gelu(acc+bias)
// EPI 3: bf16 = acc        4: bf16 = acc * dinv[z][row]
// EPI 5: split-K partials  6: fused QKV: route by col>>10 into 3 contiguous buffers
template<int BM,int BN,int WR,int WC,int EPI,bool XS>
__global__ __launch_bounds__(256) void gemm_k(
    const u16* __restrict__ A, int lda, long sA,
    const u16* __restrict__ W, int ldw, long sW,
    const float* __restrict__ bias,
    void* __restrict__ Cv, int ldc, long sCb, long sCh,
    const float* __restrict__ dinv, int K)
{
  static_assert(WR*WC==4, "4 waves");
  constexpr int WM=BM/WR, WN=BN/WC, MI=WM/16, NI=WN/16;
  __shared__ __align__(16) u16 As[BM*64];
  __shared__ __align__(16) u16 Ws[BN*64];
  int t=threadIdx.x, z=blockIdx.z;
  int bx, by;
  if (XS){
    unsigned gx=gridDim.x, flat=blockIdx.y*gx+blockIdx.x;
    unsigned cpx=(gx*gridDim.y)>>3;
    unsigned s=(flat&7)*cpx + (flat>>3);
    bx = s % gx; by = s / gx;     // consecutive s sweep col-tiles -> A-panel + W stay L2-resident per XCD
  } else { bx = blockIdx.x; by = blockIdx.y; }
  int bxn = (EPI==5) ? 0 : bx;
  int kb0 = (EPI==5) ? bx*K : 0;
  const u16* Ab = A + (long)z*sA + (long)by*BM*lda;
  const u16* Wb = W + (long)z*sW + (long)bxn*BN*ldw;
  int w=t>>6, lane=t&63, lr=lane&15, lg=lane>>4;
  int wr=w/WC, wc=w%WC;
  int srow=lane>>3, swcol=((lane&7)^srow)*8;   // swizzled global source col (halfwords)
  f32x4 acc[MI][NI];
  #pragma unroll
  for (int mi=0;mi<MI;mi++)
    #pragma unroll
    for(int ni=0;ni<NI;ni++) acc[mi][ni]=(f32x4){0.f,0.f,0.f,0.f};

  for (int k0=kb0;k0<kb0+K;k0+=64){
    #pragma unroll
    for (int i=0;i<BM/32;i++){
      int rb=w*(BM/4)+i*8;
      gload16(Ab + (long)(rb+srow)*lda + k0 + swcol, As + rb*64);
    }
    #pragma unroll
    for (int i=0;i<BN/32;i++){
      int rb=w*(BN/4)+i*8;
      gload16(Wb + (long)(rb+srow)*ldw + k0 + swcol, Ws + rb*64);
    }
    __syncthreads();
    #pragma unroll
    for (int ks=0;ks<2;ks++){
      bf16x8 aF[MI], bF[NI];
      #pragma unroll
      for (int mi=0;mi<MI;mi++){
        int row=wr*WM+mi*16+lr;
        aF[mi]=*(const bf16x8*)((const char*)As + (row<<7) + ((((ks<<2)+lg)<<4)^((row&7)<<4)));
      }
      #pragma unroll
      for (int ni=0;ni<NI;ni++){
        int row=wc*WN+ni*16+lr;
        bF[ni]=*(const bf16x8*)((const char*)Ws + (row<<7) + ((((ks<<2)+lg)<<4)^((row&7)<<4)));
      }
      #pragma unroll
      for (int mi=0;mi<MI;mi++)
        #pragma unroll
        for (int ni=0;ni<NI;ni++)
          acc[mi][ni]=__builtin_amdgcn_mfma_f32_16x16x32_bf16(aF[mi],bF[ni],acc[mi][ni],0,0,0);
    }
    __syncthreads();
  }

  long coff = (long)(z>>4)*sCb + (long)(z&15)*sCh;
  #pragma unroll
  for (int mi=0;mi<MI;mi++){
    #pragma unroll
    for (int ni=0;ni<NI;ni++){
      int col = bxn*BN + wc*WN + ni*16 + lr;
      float bv = (EPI<=2 || EPI==6) ? bias[col] : 0.0f;
      #pragma unroll
      for (int r=0;r<4;r++){
        int row = by*BM + wr*WM + mi*16 + lg*4 + r;
        float v = acc[mi][ni][r];
        if (EPI==0){
          ((u16*)Cv)[coff + (long)row*ldc + col] = f2b(v+bv);
        } else if (EPI==1){
          ((float*)Cv)[coff + (long)row*ldc + col] += v+bv;
        } else if (EPI==2){
          float u=v+bv;
          ((u16*)Cv)[coff + (long)row*ldc + col] = f2b(0.5f*u*(1.0f+erff(u*0.70710678118654752f)));
        } else if (EPI==3){
          ((u16*)Cv)[coff + (long)row*ldc + col] = f2b(v);
        } else if (EPI==4){
          ((u16*)Cv)[coff + (long)row*ldc + col] = f2b(v*dinv[(long)z*N_ + row]);
        } else if (EPI==5){
          ((float*)Cv)[((long)z*gridDim.x + bx)*((long)BM*ldc) + (long)row*ldc + col] = v;
        } else {
          int seg = col>>10, c = col&1023;
          ((u16*)Cv)[(long)seg*((long)ROWS_*D_) + (long)row*D_ + c] = f2b(v+bv);
        }
      }
    }
  }
}

// =================================================================
struct WS {
  u16 *wbuf, *pjb, *hb, *qb, *kb, *pbuf, *sh16, *ctxT;
  float *fbias, *part, *dgq, *dgkdnv, *ksm; unsigned* sky;
  size_t total;
};
static WS plan_ws(char* base, int CH){
  WS w; size_t off=0;
  auto al=[&](size_t b)->char*{ char* p=base+off; off=(off+b+255)&~(size_t)255; return p; };
  const size_t TB=(size_t)ROWS_*D_*2;
  w.wbuf=(u16*)al(6ull*D_*D_*2);
  w.pjb =(u16*)al((size_t)L_*M_*DH_*2);
  w.fbias=(float*)al(3*D_*4);
  w.hb  =(u16*)al(TB);
  // qb, kb, pbuf MUST be contiguous (fused-QKV epilogue: seg*ROWS_*D_)
  w.qb  =(u16*)al(TB);
  w.kb  =(u16*)al(TB);
  size_t pb=(size_t)CH*M_*N_*2; if (pb<TB) pb=TB;   // also hosts vb (seg 2)
  w.pbuf=(u16*)al(pb);
  w.sh16=(u16*)al(TB);
  w.part=(float*)al((size_t)CH*SPLIT_*DH_*M_*4);
  w.ctxT=(u16*)al((size_t)BH_*DH_*M_*2);
  w.dgq =(float*)al((size_t)BH_*N_*4);
  w.dgkdnv=(float*)al((size_t)BH_*N_*4);
  w.ksm =(float*)al((size_t)BH_*M_*4);
  w.sky =(unsigned*)al(BH_*4);
  w.total=off;
  return w;
}

extern "C" void kernel_launch(void* const* d_in, const int* in_sizes, int n_in,
                              void* d_out, int out_size, void* d_ws, size_t ws_size,
                              hipStream_t stream)
{
  const float* x    = (const float*)d_in[0];
  const float* proj = (const float*)d_in[1];
  const float* ln1g = (const float*)d_in[2];
  const float* ln1b = (const float*)d_in[3];
  const float* Wq   = (const float*)d_in[4];
  const float* bq   = (const float*)d_in[5];
  const float* Wk   = (const float*)d_in[6];
  const float* bk   = (const float*)d_in[7];
  const float* Wv   = (const float*)d_in[8];
  const float* bv   = (const float*)d_in[9];
  const float* Wo   = (const float*)d_in[10];
  const float* bo   = (const float*)d_in[11];
  const float* ln2g = (const float*)d_in[12];
  const float* ln2b = (const float*)d_in[13];
  const float* W1   = (const float*)d_in[14];
  const float* b1   = (const float*)d_in[15];
  const float* W2   = (const float*)d_in[16];
  const float* b2   = (const float*)d_in[17];

  char* base=(char*)d_ws;
  int CH=64;
  WS w = plan_ws(base, 64);
  if (w.total > ws_size){ CH=16; w = plan_ws(base, 16); }
  if (w.total > ws_size){
    fillf_k<<<(out_size+255)/256,256,0,stream>>>((float*)d_out,(long)out_size,(float)(ws_size>>20));
    return;
  }
  const int NCH = BH_/CH;

  u16* vb = w.pbuf;     // alias: V output (seg 2 of fused QKV), dead before kp_t written
  u16* vt = w.sh16;     // alias: v_t, dead before tm written
  u16* at = w.hb;       // alias: attn out, hb dead between QKV-GEMM and ln2
  u16* tm = w.sh16;     // alias: FFN intermediate
  float* dnv = w.dgkdnv;// alias: dgk dead before dinv written

  wcvt_k<<<(L_*M_*DH_/4+255)/256,256,0,stream>>>(proj,w.pjb,(long)L_*M_*DH_);
  hipMemcpyAsync(d_out, x, (size_t)ROWS_*D_*4, hipMemcpyDeviceToDevice, stream);
  float* Xc = (float*)d_out;

  const long wn = (long)D_*D_;
  const int wg = (int)(wn/4/256);
  dim3 gBig(D_/128, ROWS_/64, 1);        // 8 x 128 = 1024 blocks = 4/CU
  dim3 gQKV(3*D_/128, ROWS_/64, 1);      // 24 x 128 = 3072 blocks

  for (int l=0;l<L_;l++){
    u16* wqkv=w.wbuf;         // wq|wk|wv contiguous = fused 3072x1024
    u16* wo=w.wbuf+3*wn;      u16* w1=w.wbuf+4*wn; u16* w2=w.wbuf+5*wn;
    wcvt_k<<<wg,256,0,stream>>>(Wq+(size_t)l*wn,w.wbuf,wn);
    wcvt_k<<<wg,256,0,stream>>>(Wk+(size_t)l*wn,w.wbuf+wn,wn);
    wcvt_k<<<wg,256,0,stream>>>(Wv+(size_t)l*wn,w.wbuf+2*wn,wn);
    wcvt_k<<<wg,256,0,stream>>>(Wo+(size_t)l*wn,wo,wn);
    wcvt_k<<<wg,256,0,stream>>>(W1+(size_t)l*wn,w1,wn);
    wcvt_k<<<wg,256,0,stream>>>(W2+(size_t)l*wn,w2,wn);
    hipMemcpyAsync(w.fbias,       bq+(size_t)l*D_, D_*4, hipMemcpyDeviceToDevice, stream);
    hipMemcpyAsync(w.fbias+D_,    bk+(size_t)l*D_, D_*4, hipMemcpyDeviceToDevice, stream);
    hipMemcpyAsync(w.fbias+2*D_,  bv+(size_t)l*D_, D_*4, hipMemcpyDeviceToDevice, stream);
    const u16* pj = w.pjb + (size_t)l*M_*DH_;

    ln_k<<<ROWS_,256,0,stream>>>(Xc, ln1g+(size_t)l*D_, ln1b+(size_t)l*D_, w.hb);
    // fused QKV: C routed by col>>10 into qb|kb|pbuf (contiguous)
    gemm_k<64,128,1,4,6,true><<<gQKV,256,0,stream>>>(w.hb,D_,0, wqkv,D_,0, w.fbias, w.qb,D_,0,0,nullptr,D_);
    vt_k<<<dim3(N_/64,BH_),256,0,stream>>>(vb, vt);
    diagk_k<<<BH_*N_/4,256,0,stream>>>(w.qb, w.dgq);
    diagk_k<<<BH_*N_/4,256,0,stream>>>(w.kb, w.dgkdnv);
    sinit_k<<<1,64,0,stream>>>(w.sky);

    for (int ch=0; ch<NCH; ch++){
      int zoff = ch*CH;
      u16* kq = w.pbuf;   // chunk-local kp_t then qp
      dd_k<0><<<dim3(N_/64,CH),256,0,stream>>>(w.kb,pj,nullptr,w.sky,nullptr,zoff);
      dd_k<1><<<dim3(N_/64,CH),256,0,stream>>>(w.kb,pj,w.dgkdnv+(long)zoff*N_,w.sky,kq,zoff);
      ksum_k<<<CH*M_/4,256,0,stream>>>(kq, w.ksm+(long)zoff*M_);
      gemm_k<64,256,1,4,5,false><<<dim3(SPLIT_,1,CH),256,0,stream>>>(
          vt+(long)zoff*DH_*N_, N_, (long)DH_*N_,
          kq, N_, (long)M_*N_, nullptr,
          w.part, M_, 0,0, nullptr, N_/SPLIT_);
      ctxred_k<<<CH*DH_*M_/256,256,0,stream>>>(w.part, w.ctxT+(long)zoff*DH_*M_);
      dd_k<2><<<dim3(N_/64,CH),256,0,stream>>>(w.qb,pj,w.dgq+(long)zoff*N_,w.sky,kq,zoff);
      dinv_k<<<CH*N_/4,256,0,stream>>>(kq, w.ksm+(long)zoff*M_, dnv+(long)zoff*N_);
      gemm_k<128,64,2,2,4,false><<<dim3(1,N_/128,CH),256,0,stream>>>(
          kq, M_, (long)N_*M_,
          w.ctxT+(long)zoff*DH_*M_, M_, (long)DH_*M_, nullptr,
          at+(long)(zoff>>4)*N_*D_, D_, (long)N_*D_, (long)DH_, dnv+(long)zoff*N_, M_);
    }

    gemm_k<64,128,1,4,1,true><<<gBig,256,0,stream>>>(at,D_,0, wo,D_,0, bo+(size_t)l*D_, Xc,D_,0,0,nullptr,D_);
    ln_k<<<ROWS_,256,0,stream>>>(Xc, ln2g+(size_t)l*D_, ln2b+(size_t)l*D_, w.hb);
    gemm_k<64,128,1,4,2,true><<<gBig,256,0,stream>>>(w.hb,D_,0, w1,D_,0, b1+(size_t)l*D_, tm,D_,0,0,nullptr,D_);
    gemm_k<64,128,1,4,1,true><<<gBig,256,0,stream>>>(tm,D_,0, w2,D_,0, b2+(size_t)l*D_, Xc,D_,0,0,nullptr,D_);
  }
}

// Round 6
// 1566.844 us; speedup vs baseline: 1.3690x; 1.0233x over previous
//
#include <hip/hip_runtime.h>

#define B_    4
#define N_    2048
#define D_    1024
#define L_    4
#define M_    256
#define DH_   64
#define H_    16
#define BH_   64      // B_*H_
#define ROWS_ 8192    // B_*N_

typedef __bf16 bf16x8 __attribute__((ext_vector_type(8)));
typedef float  f32x4  __attribute__((ext_vector_type(4)));
typedef unsigned short u16;

__device__ __forceinline__ u16 f2b(float f){
  unsigned u = __float_as_uint(f);
  u += 0x7FFFu + ((u >> 16) & 1u);          // RNE
  return (u16)(u >> 16);
}
__device__ __forceinline__ float b2f(u16 h){ return __uint_as_float(((unsigned)h) << 16); }
__device__ __forceinline__ unsigned fkey(float x){
  unsigned u = __float_as_uint(x);
  return (u & 0x80000000u) ? ~u : (u | 0x80000000u);
}
__device__ __forceinline__ float fdec(unsigned k){
  unsigned u = (k & 0x80000000u) ? (k ^ 0x80000000u) : ~k;
  return __uint_as_float(u);
}

// global -> LDS direct, 16B per lane. LDS dest is wave-uniform base + lane*16.
__device__ __forceinline__ void gload16(const u16* g, u16* l){
  __builtin_amdgcn_global_load_lds(
      (const __attribute__((address_space(1))) void*)g,
      (__attribute__((address_space(3))) void*)l, 16, 0, 0);
}

// ---------------- fp32 -> bf16 convert ----------------
__global__ __launch_bounds__(256) void wcvt_k(const float* __restrict__ s, u16* __restrict__ d, long n){
  long i = ((long)blockIdx.x*256 + threadIdx.x)*4;
  if (i+3 < n){
    float4 v = *(const float4*)(s+i);
    d[i]=f2b(v.x); d[i+1]=f2b(v.y); d[i+2]=f2b(v.z); d[i+3]=f2b(v.w);
  } else {
    for(long j=i;j<n;j++) d[j]=f2b(s[j]);
  }
}

// ---------------- diagnostic fill ----------------
__global__ void fillf_k(float* o, long n, float v){
  long i=(long)blockIdx.x*256+threadIdx.x; if(i<n) o[i]=v;
}

// ---------------- LayerNorm: fp32 row -> bf16 row ----------------
__global__ __launch_bounds__(256) void ln_k(const float* __restrict__ x,
    const float* __restrict__ g, const float* __restrict__ bt, u16* __restrict__ h){
  int row = blockIdx.x, t = threadIdx.x;
  const float* xr = x + (long)row*D_;
  float4 v = *(const float4*)(xr + t*4);
  float s  = v.x+v.y+v.z+v.w;
  float ss = v.x*v.x+v.y*v.y+v.z*v.z+v.w*v.w;
  #pragma unroll
  for (int m=1;m<64;m<<=1){ s += __shfl_xor(s,m); ss += __shfl_xor(ss,m); }
  __shared__ float ps[4][2];
  int w=t>>6;
  if ((t&63)==0){ ps[w][0]=s; ps[w][1]=ss; }
  __syncthreads();
  s  = ps[0][0]+ps[1][0]+ps[2][0]+ps[3][0];
  ss = ps[0][1]+ps[1][1]+ps[2][1]+ps[3][1];
  float mean = s*(1.0f/D_);
  float rs = rsqrtf(ss*(1.0f/D_) - mean*mean + 1e-5f);
  int c=t*4;
  u16* hr = h + (long)row*D_;
  hr[c+0]=f2b((v.x-mean)*rs*g[c+0]+bt[c+0]);
  hr[c+1]=f2b((v.y-mean)*rs*g[c+1]+bt[c+1]);
  hr[c+2]=f2b((v.z-mean)*rs*g[c+2]+bt[c+2]);
  hr[c+3]=f2b((v.w-mean)*rs*g[c+3]+bt[c+3]);
}

// ---------------- diag[z][n] = sum_d x^2 / 16 ----------------
__global__ __launch_bounds__(256) void diagk_k(const u16* __restrict__ X, float* __restrict__ dg){
  int t=threadIdx.x, w=t>>6, lane=t&63;
  long r=(long)blockIdx.x*4+w;           // r = z*N_ + n
  int z=(int)(r>>11), n=(int)(r&2047);
  int b=z>>4, hh=z&15;
  float v=b2f(X[((long)b*N_+n)*D_ + hh*DH_ + lane]);
  float sq=v*v;
  #pragma unroll
  for (int m=1;m<64;m<<=1) sq += __shfl_xor(sq,m);
  if (lane==0) dg[r]=sq*0.0625f;
}

// ---------------- v (B,N,H,dh) -> v_t [z][d][n] ----------------
__global__ __launch_bounds__(256) void vt_k(const u16* __restrict__ V, u16* __restrict__ Vt){
  __shared__ __align__(16) u16 ts[64][72];
  int t=threadIdx.x, z=blockIdx.y, n0=blockIdx.x*64;
  int b=z>>4, hh=z&15;
  {
    int row=t>>2, c16=(t&3)*16;
    const u16* src = V + ((long)b*N_ + n0+row)*D_ + hh*DH_ + c16;
    *(uint4*)&ts[row][c16]   = *(const uint4*)src;
    *(uint4*)&ts[row][c16+8] = *(const uint4*)(src+8);
  }
  __syncthreads();
  {
    int d=t>>2, nc=(t&3)*16;
    union { u16 u[16]; uint4 q[2]; } tmp;
    #pragma unroll
    for (int j=0;j<16;j++) tmp.u[j]=ts[nc+j][d];
    u16* dst = Vt + (long)z*DH_*N_ + (long)d*N_ + n0+nc;
    *(uint4*)dst = tmp.q[0];
    *(uint4*)(dst+8) = tmp.q[1];
  }
}

// ================= FAVOR fused kernels =================
// shared staging helpers (proj 256x64 swizzled / X 64x64 swizzled)
#define STAGE_PS(Ps, P) \
  _Pragma("unroll") \
  for (int i=0;i<8;i++){ \
    int c=threadIdx.x+i*256, row=c>>3, c8=c&7; \
    uint4 dv = *(const uint4*)((P) + row*64 + c8*8); \
    *(uint4*)((char*)(Ps) + (row<<7) + ((c8<<4)^((row&7)<<4))) = dv; \
  }
#define STAGE_XS(Xs, X, b, hh, n0) \
  _Pragma("unroll") \
  for (int i=0;i<2;i++){ \
    int c=threadIdx.x+i*256, row=c>>3, c8=c&7; \
    uint4 dv = *(const uint4*)((X) + ((long)(b)*N_ + (n0)+row)*D_ + (hh)*DH_ + c8*8); \
    *(uint4*)((char*)(Xs) + (row<<7) + ((c8<<4)^((row&7)<<4))) = dv; \
  }
#define DD_MFMA(acc, Xs, Ps, w, lr, lg) \
  _Pragma("unroll") \
  for (int ks=0;ks<2;ks++){ \
    bf16x8 aF[4], bF[4]; \
    _Pragma("unroll") \
    for (int mi=0;mi<4;mi++){ \
      int row=mi*16+(lr); \
      aF[mi]=*(const bf16x8*)((const char*)(Xs) + (row<<7) + ((((ks<<2)+(lg))<<4)^((row&7)<<4))); \
    } \
    _Pragma("unroll") \
    for (int ni=0;ni<4;ni++){ \
      int row=(w)*64+ni*16+(lr); \
      bF[ni]=*(const bf16x8*)((const char*)(Ps) + (row<<7) + ((((ks<<2)+(lg))<<4)^((row&7)<<4))); \
    } \
    _Pragma("unroll") \
    for (int mi=0;mi<4;mi++) \
      _Pragma("unroll") \
      for (int ni=0;ni<4;ni++) \
        acc[mi][ni]=__builtin_amdgcn_mfma_f32_16x16x32_bf16(aF[mi],bF[ni],acc[mi][ni],0,0,0); \
  }

// ---- stab: global max of dd(K) per head -> atomicMax key ----
__global__ __launch_bounds__(256) void ddstab_k(
    const u16* __restrict__ X, const u16* __restrict__ P,
    unsigned* __restrict__ sk, int zoff)
{
  __shared__ __align__(16) char smem[46080];
  u16* Ps=(u16*)smem; u16* Xs=(u16*)(smem+36864); float* rm=(float*)(smem+45056);
  int t=threadIdx.x, w=t>>6, lane=t&63, lr=lane&15, lg=lane>>4;
  int zg=blockIdx.y+zoff, n0=blockIdx.x*64;
  int b=zg>>4, hh=zg&15;
  STAGE_PS(Ps, P); STAGE_XS(Xs, X, b, hh, n0);
  __syncthreads();
  f32x4 acc[4][4];
  #pragma unroll
  for (int mi=0;mi<4;mi++)
    #pragma unroll
    for (int ni=0;ni<4;ni++) acc[mi][ni]=(f32x4){0.f,0.f,0.f,0.f};
  DD_MFMA(acc, Xs, Ps, w, lr, lg);
  float mx = acc[0][0][0];
  #pragma unroll
  for (int mi=0;mi<4;mi++)
    #pragma unroll
    for (int ni=0;ni<4;ni++)
      #pragma unroll
      for (int r=0;r<4;r++) mx=fmaxf(mx,acc[mi][ni][r]);
  #pragma unroll
  for (int m=1;m<64;m<<=1) mx = fmaxf(mx, __shfl_xor(mx,m));
  if (lane==0) rm[w]=mx;
  __syncthreads();
  const float SN = 0.35355339059327373f;
  if (t==0) atomicMax(sk+zg, fkey(SN*fmaxf(fmaxf(rm[0],rm[1]),fmaxf(rm[2],rm[3]))));
}

// ---- fused: dd(K)+exp -> kp ; ksum partial ; ctx partial = kp^T . v ----
// grid (8, CH): block = slot of 256 n rows. part[zl][slot][256 m][64 d] fp32.
__global__ __launch_bounds__(256) void ddctx_k(
    const u16* __restrict__ Kb, const u16* __restrict__ P,
    const u16* __restrict__ Vt, const float* __restrict__ dg,
    const unsigned* __restrict__ sk,
    float* __restrict__ part, float* __restrict__ kspart, int zoff)
{
  __shared__ __align__(16) char smem[54272];
  u16* Ps = (u16*)smem;               // [0,32768) per-subtile proj
  u16* Tr = (u16*)smem;               // [0,36864) kp^T overlay (256x72)
  u16* Xs = (u16*)(smem+36864);       // 8KB
  u16* Vs = (u16*)(smem+45056);       // [64][72] v^T tile
  int t=threadIdx.x, w=t>>6, lane=t&63, lr=lane&15, lg=lane>>4;
  int zl=blockIdx.y, zg=zl+zoff, slot=blockIdx.x;
  int b=zg>>4, hh=zg&15;
  const float SN = 0.35355339059327373f;
  float stab = fdec(sk[zg]);
  const float* dgz0 = dg + (long)zl*N_;

  f32x4 cacc[4][4];
  #pragma unroll
  for (int mi=0;mi<4;mi++)
    #pragma unroll
    for (int ni=0;ni<4;ni++) cacc[mi][ni]=(f32x4){0.f,0.f,0.f,0.f};
  float ksp[4]={0.f,0.f,0.f,0.f};

  for (int s=0;s<4;++s){
    int n0 = slot*256 + s*64;
    STAGE_PS(Ps, P); STAGE_XS(Xs, Kb, b, hh, n0);
    {
      int d=t>>2, nc=(t&3)*16;
      const u16* src = Vt + (long)zg*DH_*N_ + (long)d*N_ + n0 + nc;
      *(uint4*)&Vs[d*72+nc]   = *(const uint4*)src;
      *(uint4*)&Vs[d*72+nc+8] = *(const uint4*)(src+8);
    }
    __syncthreads();
    f32x4 acc[4][4];
    #pragma unroll
    for (int mi=0;mi<4;mi++)
      #pragma unroll
      for (int ni=0;ni<4;ni++) acc[mi][ni]=(f32x4){0.f,0.f,0.f,0.f};
    DD_MFMA(acc, Xs, Ps, w, lr, lg);
    __syncthreads();                       // Ps reads done before Tr overwrite
    const float* dgz = dgz0 + n0;
    #pragma unroll
    for (int mi=0;mi<4;mi++)
      #pragma unroll
      for (int ni=0;ni<4;ni++){
        int col = w*64+ni*16+lr;
        #pragma unroll
        for (int r=0;r<4;r++){
          int rw = mi*16+lg*4+r;
          float kp = 0.0625f*(expf(SN*acc[mi][ni][r] - dgz[rw] - stab) + 1e-4f);
          Tr[col*72+rw] = f2b(kp);
          ksp[ni] += kp;
        }
      }
    __syncthreads();                       // Tr ready
    // ctx MFMA: A = Tr rows m (wave slice), B = Vs rows d, K=64
    #pragma unroll
    for (int ks=0;ks<2;ks++){
      bf16x8 aF[4], bF[4];
      #pragma unroll
      for (int mi=0;mi<4;mi++)
        aF[mi]=*(const bf16x8*)(Tr + (w*64+mi*16+lr)*72 + ks*32 + lg*8);
      #pragma unroll
      for (int ni=0;ni<4;ni++)
        bF[ni]=*(const bf16x8*)(Vs + (ni*16+lr)*72 + ks*32 + lg*8);
      #pragma unroll
      for (int mi=0;mi<4;mi++)
        #pragma unroll
        for (int ni=0;ni<4;ni++)
          cacc[mi][ni]=__builtin_amdgcn_mfma_f32_16x16x32_bf16(aF[mi],bF[ni],cacc[mi][ni],0,0,0);
    }
    __syncthreads();                       // before next subtile restage
  }
  // ksum partial: complete over lg groups
  #pragma unroll
  for (int ni=0;ni<4;ni++){
    ksp[ni] += __shfl_xor(ksp[ni],16);
    ksp[ni] += __shfl_xor(ksp[ni],32);
  }
  if (lane<16){
    float* kb_ = kspart + ((long)zl*8+slot)*256;
    #pragma unroll
    for (int ni=0;ni<4;ni++) kb_[w*64+ni*16+lane] = ksp[ni];
  }
  float* pb = part + ((long)zl*8+slot)*16384;
  #pragma unroll
  for (int mi=0;mi<4;mi++)
    #pragma unroll
    for (int ni=0;ni<4;ni++){
      int d = ni*16+lr;
      #pragma unroll
      for (int r=0;r<4;r++){
        int m = w*64+mi*16+lg*4+r;
        pb[m*64+d] = cacc[mi][ni][r];
      }
    }
}

// ---- reduce 8 slots -> ksm[z][m] fp32 ; ctxT[z][d][m] bf16 (transposed) ----
__global__ __launch_bounds__(256) void ctxred2_k(
    const float* __restrict__ part, const float* __restrict__ kspart,
    u16* __restrict__ ctxT, float* __restrict__ ksm)
{
  int z = blockIdx.x, t = threadIdx.x;
  const float* pz = part + (long)z*8*16384;
  const float* kz = kspart + (long)z*8*256;
  float s=0.f;
  #pragma unroll
  for (int s8=0;s8<8;s8++) s += kz[s8*256+t];
  ksm[(long)z*256+t]=s;
  f32x4 r4[16];
  #pragma unroll
  for (int j=0;j<16;j++) r4[j] = *(const f32x4*)(pz + (long)t*64 + j*4);
  #pragma unroll
  for (int s8=1;s8<8;s8++){
    const float* ps = pz + (long)s8*16384 + (long)t*64;
    #pragma unroll
    for (int j=0;j<16;j++) r4[j] += *(const f32x4*)(ps + j*4);
  }
  u16 rb[64];
  #pragma unroll
  for (int j=0;j<16;j++){
    rb[j*4+0]=f2b(r4[j][0]); rb[j*4+1]=f2b(r4[j][1]);
    rb[j*4+2]=f2b(r4[j][2]); rb[j*4+3]=f2b(r4[j][3]);
  }
  __shared__ __align__(16) u16 TT[64][72];
  u16* co = ctxT + (long)z*16384;
  for (int c=0;c<4;c++){
    __syncthreads();
    if ((t>>6)==c){
      int r=t&63;
      #pragma unroll
      for (int j=0;j<64;j+=8) *(uint4*)&TT[r][j] = *(const uint4*)&rb[j];
    }
    __syncthreads();
    int d=t>>2, mq=(t&3)*16;
    union { u16 u[16]; uint4 q[2]; } tmp;
    #pragma unroll
    for (int j=0;j<16;j++) tmp.u[j]=TT[mq+j][d];
    *(uint4*)(co + d*256 + c*64 + mq)     = tmp.q[0];
    *(uint4*)(co + d*256 + c*64 + mq + 8) = tmp.q[1];
  }
}

// ---- fused: dd(Q)+rowmax+exp -> qp(LDS) ; dinv in-block ; out = dinv*(qp.ctxT) ----
// grid (32, CH). ctxT/ksm/dg are chunk-local bases.
__global__ __launch_bounds__(256) void ddq_attn_k(
    const u16* __restrict__ Qb, const u16* __restrict__ P,
    const float* __restrict__ dg, const float* __restrict__ ksm,
    const u16* __restrict__ ctxT, u16* __restrict__ at, int zoff)
{
  __shared__ __align__(16) char smem[46080];
  u16*   Ps  = (u16*)smem;                 // dd phase
  u16*   qpL = (u16*)smem;                 // [64][264] overlay (33792B)
  float* rdot= (float*)(smem+33792);       // [256]
  float* dnvs= (float*)(smem+34816);       // [64]
  u16*   Xs  = (u16*)(smem+36864);
  float* rm  = (float*)(smem+45056);       // [256]
  int t=threadIdx.x, w=t>>6, lane=t&63, lr=lane&15, lg=lane>>4;
  int zl=blockIdx.y, zg=zl+zoff, n0=blockIdx.x*64;
  int b=zg>>4, hh=zg&15;
  const float SN = 0.35355339059327373f;

  STAGE_PS(Ps, P); STAGE_XS(Xs, Qb, b, hh, n0);
  __syncthreads();
  f32x4 acc[4][4];
  #pragma unroll
  for (int mi=0;mi<4;mi++)
    #pragma unroll
    for (int ni=0;ni<4;ni++) acc[mi][ni]=(f32x4){0.f,0.f,0.f,0.f};
  DD_MFMA(acc, Xs, Ps, w, lr, lg);
  // per-row max within wave slice
  float rmx[4][4];
  #pragma unroll
  for (int mi=0;mi<4;mi++)
    #pragma unroll
    for (int r=0;r<4;r++){
      float v = acc[mi][0][r];
      #pragma unroll
      for (int ni=1;ni<4;ni++) v=fmaxf(v, acc[mi][ni][r]);
      #pragma unroll
      for (int m=1;m<16;m<<=1) v = fmaxf(v, __shfl_xor(v,m));
      rmx[mi][r]=v;
    }
  if (lr==0){
    #pragma unroll
    for (int mi=0;mi<4;mi++)
      #pragma unroll
      for (int r=0;r<4;r++) rm[w*64 + mi*16 + lg*4 + r] = rmx[mi][r];
  }
  __syncthreads();                         // Ps reads done; rm ready
  const float* dgz = dg + (long)zl*N_ + n0;
  const float* ksz = ksm + (long)zl*256;
  float kcol[4];
  #pragma unroll
  for (int ni=0;ni<4;ni++) kcol[ni] = ksz[w*64+ni*16+lr];
  float rd[4][4];
  #pragma unroll
  for (int mi=0;mi<4;mi++)
    #pragma unroll
    for (int r=0;r<4;r++){
      int rw = mi*16+lg*4+r;
      float st = fmaxf(fmaxf(rm[rw],rm[64+rw]),fmaxf(rm[128+rw],rm[192+rw]));
      float dgv = dgz[rw];
      float rsum = 0.f;
      #pragma unroll
      for (int ni=0;ni<4;ni++){
        int col = w*64+ni*16+lr;
        float qpv = 0.0625f*(expf(SN*acc[mi][ni][r] - dgv - SN*st) + 1e-4f);
        qpL[rw*264+col] = f2b(qpv);
        rsum += qpv*kcol[ni];
      }
      rd[mi][r]=rsum;
    }
  #pragma unroll
  for (int mi=0;mi<4;mi++)
    #pragma unroll
    for (int r=0;r<4;r++){
      #pragma unroll
      for (int m=1;m<16;m<<=1) rd[mi][r] += __shfl_xor(rd[mi][r],m);
    }
  if (lr==0){
    #pragma unroll
    for (int mi=0;mi<4;mi++)
      #pragma unroll
      for (int r=0;r<4;r++) rdot[w*64 + mi*16+lg*4+r] = rd[mi][r];
  }
  __syncthreads();
  if (t<64) dnvs[t] = 1.0f/(rdot[t]+rdot[64+t]+rdot[128+t]+rdot[192+t]);
  __syncthreads();
  // attn MFMA: wave w -> n rows [w*16, w*16+16), K=256 over m, N=64 d
  const u16* cz = ctxT + (long)zl*16384;
  f32x4 aacc[4];
  #pragma unroll
  for (int ni=0;ni<4;ni++) aacc[ni]=(f32x4){0.f,0.f,0.f,0.f};
  #pragma unroll
  for (int ks=0;ks<8;ks++){
    bf16x8 aF = *(const bf16x8*)(qpL + (w*16+lr)*264 + ks*32 + lg*8);
    #pragma unroll
    for (int ni=0;ni<4;ni++){
      bf16x8 bF = *(const bf16x8*)(cz + (ni*16+lr)*256 + ks*32 + lg*8);
      aacc[ni]=__builtin_amdgcn_mfma_f32_16x16x32_bf16(aF,bF,aacc[ni],0,0,0);
    }
  }
  #pragma unroll
  for (int ni=0;ni<4;ni++){
    #pragma unroll
    for (int r=0;r<4;r++){
      int n = n0 + w*16 + lg*4 + r;
      at[((long)b*N_ + n)*D_ + hh*64 + ni*16 + lr] = f2b(aacc[ni][r]*dnvs[w*16+lg*4+r]);
    }
  }
}

// ---------------- generic bf16 MFMA GEMM: C = A(MxK) * W(NxK)^T ----------------
// Both operands via global_load_lds (linear LDS dest) with pre-swizzled GLOBAL
// source column; reads apply the same XOR -> 2-way bank aliasing = free.
// EPI 0: bf16 = acc+bias   1: f32 resid += acc+bias   2: bf16 = gelu(acc+bias)
// EPI 6: fused QKV: route by col>>10 into 3 contiguous buffers
template<int BM,int BN,int WR,int WC,int EPI,bool XS>
__global__ __launch_bounds__(256) void gemm_k(
    const u16* __restrict__ A, int lda, long sA,
    const u16* __restrict__ W, int ldw, long sW,
    const float* __restrict__ bias,
    void* __restrict__ Cv, int ldc, long sCb, long sCh,
    const float* __restrict__ dinv, int K)
{
  static_assert(WR*WC==4, "4 waves");
  constexpr int WM=BM/WR, WN=BN/WC, MI=WM/16, NI=WN/16;
  __shared__ __align__(16) u16 As[BM*64];
  __shared__ __align__(16) u16 Ws[BN*64];
  int t=threadIdx.x, z=blockIdx.z;
  int bx, by;
  if (XS){
    unsigned gx=gridDim.x, flat=blockIdx.y*gx+blockIdx.x;
    unsigned cpx=(gx*gridDim.y)>>3;
    unsigned s=(flat&7)*cpx + (flat>>3);
    bx = s % gx; by = s / gx;
  } else { bx = blockIdx.x; by = blockIdx.y; }
  const u16* Ab = A + (long)z*sA + (long)by*BM*lda;
  const u16* Wb = W + (long)z*sW + (long)bx*BN*ldw;
  int w=t>>6, lane=t&63, lr=lane&15, lg=lane>>4;
  int wr=w/WC, wc=w%WC;
  int srow=lane>>3, swcol=((lane&7)^srow)*8;   // swizzled global source col
  f32x4 acc[MI][NI];
  #pragma unroll
  for (int mi=0;mi<MI;mi++)
    #pragma unroll
    for(int ni=0;ni<NI;ni++) acc[mi][ni]=(f32x4){0.f,0.f,0.f,0.f};

  for (int k0=0;k0<K;k0+=64){
    #pragma unroll
    for (int i=0;i<BM/32;i++){
      int rb=w*(BM/4)+i*8;
      gload16(Ab + (long)(rb+srow)*lda + k0 + swcol, As + rb*64);
    }
    #pragma unroll
    for (int i=0;i<BN/32;i++){
      int rb=w*(BN/4)+i*8;
      gload16(Wb + (long)(rb+srow)*ldw + k0 + swcol, Ws + rb*64);
    }
    __syncthreads();
    #pragma unroll
    for (int ks=0;ks<2;ks++){
      bf16x8 aF[MI], bF[NI];
      #pragma unroll
      for (int mi=0;mi<MI;mi++){
        int row=wr*WM+mi*16+lr;
        aF[mi]=*(const bf16x8*)((const char*)As + (row<<7) + ((((ks<<2)+lg)<<4)^((row&7)<<4)));
      }
      #pragma unroll
      for (int ni=0;ni<NI;ni++){
        int row=wc*WN+ni*16+lr;
        bF[ni]=*(const bf16x8*)((const char*)Ws + (row<<7) + ((((ks<<2)+lg)<<4)^((row&7)<<4)));
      }
      #pragma unroll
      for (int mi=0;mi<MI;mi++)
        #pragma unroll
        for (int ni=0;ni<NI;ni++)
          acc[mi][ni]=__builtin_amdgcn_mfma_f32_16x16x32_bf16(aF[mi],bF[ni],acc[mi][ni],0,0,0);
    }
    __syncthreads();
  }

  long coff = (long)(z>>4)*sCb + (long)(z&15)*sCh;
  #pragma unroll
  for (int mi=0;mi<MI;mi++){
    #pragma unroll
    for (int ni=0;ni<NI;ni++){
      int col = bx*BN + wc*WN + ni*16 + lr;
      float bv = (EPI<=2 || EPI==6) ? bias[col] : 0.0f;
      #pragma unroll
      for (int r=0;r<4;r++){
        int row = by*BM + wr*WM + mi*16 + lg*4 + r;
        float v = acc[mi][ni][r];
        if (EPI==0){
          ((u16*)Cv)[coff + (long)row*ldc + col] = f2b(v+bv);
        } else if (EPI==1){
          ((float*)Cv)[coff + (long)row*ldc + col] += v+bv;
        } else if (EPI==2){
          float u=v+bv;
          ((u16*)Cv)[coff + (long)row*ldc + col] = f2b(0.5f*u*(1.0f+erff(u*0.70710678118654752f)));
        } else {
          int seg = col>>10, c = col&1023;
          ((u16*)Cv)[(long)seg*((long)ROWS_*D_) + (long)row*D_ + c] = f2b(v+bv);
        }
      }
    }
  }
}

// =================================================================
struct WS {
  u16 *wbuf, *pjb, *hb, *qb, *kb, *pbuf, *sh16, *ctxT;
  float *fbias, *part, *kspart, *dgq, *dgk, *ksm; unsigned* sky;
  size_t total;
};
static WS plan_ws(char* base, int CH){
  WS w; size_t off=0;
  auto al=[&](size_t b)->char*{ char* p=base+off; off=(off+b+255)&~(size_t)255; return p; };
  const size_t TB=(size_t)ROWS_*D_*2;
  w.wbuf=(u16*)al(6ull*D_*D_*2);
  w.pjb =(u16*)al((size_t)L_*M_*DH_*2);
  w.fbias=(float*)al(3*D_*4);
  w.hb  =(u16*)al(TB);
  // qb, kb, pbuf MUST be contiguous (fused-QKV epilogue: seg*ROWS_*D_)
  w.qb  =(u16*)al(TB);
  w.kb  =(u16*)al(TB);
  w.pbuf=(u16*)al(TB);                  // hosts vb (seg 2)
  w.sh16=(u16*)al(TB);                  // vt / FFN intermediate
  w.part=(float*)al((size_t)CH*8*M_*DH_*4);
  w.kspart=(float*)al((size_t)CH*8*M_*4);
  w.ctxT=(u16*)al((size_t)BH_*DH_*M_*2);
  w.dgq =(float*)al((size_t)BH_*N_*4);
  w.dgk =(float*)al((size_t)BH_*N_*4);
  w.ksm =(float*)al((size_t)BH_*M_*4);
  w.sky =(unsigned*)al(BH_*4);
  w.total=off;
  return w;
}

extern "C" void kernel_launch(void* const* d_in, const int* in_sizes, int n_in,
                              void* d_out, int out_size, void* d_ws, size_t ws_size,
                              hipStream_t stream)
{
  const float* x    = (const float*)d_in[0];
  const float* proj = (const float*)d_in[1];
  const float* ln1g = (const float*)d_in[2];
  const float* ln1b = (const float*)d_in[3];
  const float* Wq   = (const float*)d_in[4];
  const float* bq   = (const float*)d_in[5];
  const float* Wk   = (const float*)d_in[6];
  const float* bk   = (const float*)d_in[7];
  const float* Wv   = (const float*)d_in[8];
  const float* bv   = (const float*)d_in[9];
  const float* Wo   = (const float*)d_in[10];
  const float* bo   = (const float*)d_in[11];
  const float* ln2g = (const float*)d_in[12];
  const float* ln2b = (const float*)d_in[13];
  const float* W1   = (const float*)d_in[14];
  const float* b1   = (const float*)d_in[15];
  const float* W2   = (const float*)d_in[16];
  const float* b2   = (const float*)d_in[17];

  char* base=(char*)d_ws;
  int CH=64;
  WS w = plan_ws(base, 64);
  if (w.total > ws_size){ CH=16; w = plan_ws(base, 16); }
  if (w.total > ws_size){
    fillf_k<<<(out_size+255)/256,256,0,stream>>>((float*)d_out,(long)out_size,(float)(ws_size>>20));
    return;
  }
  const int NCH = BH_/CH;

  u16* vb = w.pbuf;     // V output (seg 2 of fused QKV)
  u16* vt = w.sh16;     // v_t, dead before FFN intermediate
  u16* at = w.hb;       // attn out, hb dead between QKV-GEMM and ln2
  u16* tm = w.sh16;     // FFN intermediate

  wcvt_k<<<(L_*M_*DH_/4+255)/256,256,0,stream>>>(proj,w.pjb,(long)L_*M_*DH_);
  hipMemcpyAsync(d_out, x, (size_t)ROWS_*D_*4, hipMemcpyDeviceToDevice, stream);
  float* Xc = (float*)d_out;

  const long wn = (long)D_*D_;
  const int wg = (int)(wn/4/256);
  dim3 gBig(D_/128, ROWS_/64, 1);        // 8 x 128 = 1024 blocks (64x128 tile)
  dim3 gQKV(3*D_/128, ROWS_/128, 1);     // 24 x 64 = 1536 blocks (128x128 tile)

  for (int l=0;l<L_;l++){
    u16* wqkv=w.wbuf;         // wq|wk|wv contiguous = fused 3072x1024
    u16* wo=w.wbuf+3*wn;      u16* w1=w.wbuf+4*wn; u16* w2=w.wbuf+5*wn;
    wcvt_k<<<wg,256,0,stream>>>(Wq+(size_t)l*wn,w.wbuf,wn);
    wcvt_k<<<wg,256,0,stream>>>(Wk+(size_t)l*wn,w.wbuf+wn,wn);
    wcvt_k<<<wg,256,0,stream>>>(Wv+(size_t)l*wn,w.wbuf+2*wn,wn);
    wcvt_k<<<wg,256,0,stream>>>(Wo+(size_t)l*wn,wo,wn);
    wcvt_k<<<wg,256,0,stream>>>(W1+(size_t)l*wn,w1,wn);
    wcvt_k<<<wg,256,0,stream>>>(W2+(size_t)l*wn,w2,wn);
    hipMemcpyAsync(w.fbias,       bq+(size_t)l*D_, D_*4, hipMemcpyDeviceToDevice, stream);
    hipMemcpyAsync(w.fbias+D_,    bk+(size_t)l*D_, D_*4, hipMemcpyDeviceToDevice, stream);
    hipMemcpyAsync(w.fbias+2*D_,  bv+(size_t)l*D_, D_*4, hipMemcpyDeviceToDevice, stream);
    const u16* pj = w.pjb + (size_t)l*M_*DH_;

    ln_k<<<ROWS_,256,0,stream>>>(Xc, ln1g+(size_t)l*D_, ln1b+(size_t)l*D_, w.hb);
    gemm_k<128,128,2,2,6,true><<<gQKV,256,0,stream>>>(w.hb,D_,0, wqkv,D_,0, w.fbias, w.qb,D_,0,0,nullptr,D_);
    vt_k<<<dim3(N_/64,BH_),256,0,stream>>>(vb, vt);
    diagk_k<<<BH_*N_/4,256,0,stream>>>(w.qb, w.dgq);
    diagk_k<<<BH_*N_/4,256,0,stream>>>(w.kb, w.dgk);
    hipMemsetAsync(w.sky, 0, BH_*4, stream);

    for (int ch=0; ch<NCH; ch++){
      int zoff = ch*CH;
      ddstab_k<<<dim3(N_/64,CH),256,0,stream>>>(w.kb, pj, w.sky, zoff);
      ddctx_k<<<dim3(8,CH),256,0,stream>>>(w.kb, pj, vt, w.dgk+(long)zoff*N_, w.sky,
                                           w.part, w.kspart, zoff);
      ctxred2_k<<<CH,256,0,stream>>>(w.part, w.kspart,
                                     w.ctxT+(long)zoff*DH_*M_, w.ksm+(long)zoff*M_);
      ddq_attn_k<<<dim3(N_/64,CH),256,0,stream>>>(w.qb, pj, w.dgq+(long)zoff*N_,
                                                  w.ksm+(long)zoff*M_,
                                                  w.ctxT+(long)zoff*DH_*M_, at, zoff);
    }

    gemm_k<64,128,1,4,1,true><<<gBig,256,0,stream>>>(at,D_,0, wo,D_,0, bo+(size_t)l*D_, Xc,D_,0,0,nullptr,D_);
    ln_k<<<ROWS_,256,0,stream>>>(Xc, ln2g+(size_t)l*D_, ln2b+(size_t)l*D_, w.hb);
    gemm_k<64,128,1,4,2,true><<<gBig,256,0,stream>>>(w.hb,D_,0, w1,D_,0, b1+(size_t)l*D_, tm,D_,0,0,nullptr,D_);
    gemm_k<64,128,1,4,1,true><<<gBig,256,0,stream>>>(tm,D_,0, w2,D_,0, b2+(size_t)l*D_, Xc,D_,0,0,nullptr,D_);
  }
}

// Round 7
// 1382.486 us; speedup vs baseline: 1.5516x; 1.1334x over previous
//
#include <hip/hip_runtime.h>

#define B_    4
#define N_    2048
#define D_    1024
#define L_    4
#define M_    256
#define DH_   64
#define H_    16
#define BH_   64      // B_*H_
#define ROWS_ 8192    // B_*N_
#define WN_   1048576 // D_*D_ = 2^20

typedef __bf16 bf16x8 __attribute__((ext_vector_type(8)));
typedef float  f32x4  __attribute__((ext_vector_type(4)));
typedef unsigned short u16;

__device__ __forceinline__ u16 f2b(float f){
  unsigned u = __float_as_uint(f);
  u += 0x7FFFu + ((u >> 16) & 1u);          // RNE
  return (u16)(u >> 16);
}
__device__ __forceinline__ float b2f(u16 h){ return __uint_as_float(((unsigned)h) << 16); }
__device__ __forceinline__ unsigned fkey(float x){
  unsigned u = __float_as_uint(x);
  return (u & 0x80000000u) ? ~u : (u | 0x80000000u);
}
__device__ __forceinline__ float fdec(unsigned k){
  unsigned u = (k & 0x80000000u) ? (k ^ 0x80000000u) : ~k;
  return __uint_as_float(u);
}

// global -> LDS direct, 16B per lane. LDS dest is wave-uniform base + lane*16.
__device__ __forceinline__ void gload16(const u16* g, u16* l){
  __builtin_amdgcn_global_load_lds(
      (const __attribute__((address_space(1))) void*)g,
      (__attribute__((address_space(3))) void*)l, 16, 0, 0);
}

// ---------------- fp32 -> bf16 convert (linear, for proj) ----------------
__global__ __launch_bounds__(256) void wcvt_k(const float* __restrict__ s, u16* __restrict__ d, long n){
  long i = ((long)blockIdx.x*256 + threadIdx.x)*4;
  if (i+3 < n){
    float4 v = *(const float4*)(s+i);
    d[i]=f2b(v.x); d[i+1]=f2b(v.y); d[i+2]=f2b(v.z); d[i+3]=f2b(v.w);
  } else {
    for(long j=i;j<n;j++) d[j]=f2b(s[j]);
  }
}

// ---- strided convert: src[l*WN_+j] -> dbase[l*6*WN_+j]  (dbase includes type*WN_) ----
__global__ __launch_bounds__(256) void wcvt2_k(const float* __restrict__ s, u16* __restrict__ dbase, long n){
  long i = ((long)blockIdx.x*256 + threadIdx.x)*4;
  if (i < n){
    float4 v = *(const float4*)(s+i);
    long l = i >> 20, j = i & (WN_-1);
    u16* d = dbase + l*(6l*WN_) + j;
    d[0]=f2b(v.x); d[1]=f2b(v.y); d[2]=f2b(v.z); d[3]=f2b(v.w);
  }
}

// ---------------- diagnostic fill ----------------
__global__ void fillf_k(float* o, long n, float v){
  long i=(long)blockIdx.x*256+threadIdx.x; if(i<n) o[i]=v;
}

// ---------------- LayerNorm: fp32 row -> bf16 row ----------------
__global__ __launch_bounds__(256) void ln_k(const float* __restrict__ x,
    const float* __restrict__ g, const float* __restrict__ bt, u16* __restrict__ h){
  int row = blockIdx.x, t = threadIdx.x;
  const float* xr = x + (long)row*D_;
  float4 v = *(const float4*)(xr + t*4);
  float s  = v.x+v.y+v.z+v.w;
  float ss = v.x*v.x+v.y*v.y+v.z*v.z+v.w*v.w;
  #pragma unroll
  for (int m=1;m<64;m<<=1){ s += __shfl_xor(s,m); ss += __shfl_xor(ss,m); }
  __shared__ float ps[4][2];
  int w=t>>6;
  if ((t&63)==0){ ps[w][0]=s; ps[w][1]=ss; }
  __syncthreads();
  s  = ps[0][0]+ps[1][0]+ps[2][0]+ps[3][0];
  ss = ps[0][1]+ps[1][1]+ps[2][1]+ps[3][1];
  float mean = s*(1.0f/D_);
  float rs = rsqrtf(ss*(1.0f/D_) - mean*mean + 1e-5f);
  int c=t*4;
  u16* hr = h + (long)row*D_;
  hr[c+0]=f2b((v.x-mean)*rs*g[c+0]+bt[c+0]);
  hr[c+1]=f2b((v.y-mean)*rs*g[c+1]+bt[c+1]);
  hr[c+2]=f2b((v.z-mean)*rs*g[c+2]+bt[c+2]);
  hr[c+3]=f2b((v.w-mean)*rs*g[c+3]+bt[c+3]);
}

// ---------------- v (B,N,H,dh) -> v_t [z][d][n] ----------------
__global__ __launch_bounds__(256) void vt_k(const u16* __restrict__ V, u16* __restrict__ Vt){
  __shared__ __align__(16) u16 ts[64][72];
  int t=threadIdx.x, z=blockIdx.y, n0=blockIdx.x*64;
  int b=z>>4, hh=z&15;
  {
    int row=t>>2, c16=(t&3)*16;
    const u16* src = V + ((long)b*N_ + n0+row)*D_ + hh*DH_ + c16;
    *(uint4*)&ts[row][c16]   = *(const uint4*)src;
    *(uint4*)&ts[row][c16+8] = *(const uint4*)(src+8);
  }
  __syncthreads();
  {
    int d=t>>2, nc=(t&3)*16;
    union { u16 u[16]; uint4 q[2]; } tmp;
    #pragma unroll
    for (int j=0;j<16;j++) tmp.u[j]=ts[nc+j][d];
    u16* dst = Vt + (long)z*DH_*N_ + (long)d*N_ + n0+nc;
    *(uint4*)dst = tmp.q[0];
    *(uint4*)(dst+8) = tmp.q[1];
  }
}

// ================= FAVOR fused kernels =================
#define STAGE_PS(Ps, P) \
  _Pragma("unroll") \
  for (int i=0;i<8;i++){ \
    int c=threadIdx.x+i*256, row=c>>3, c8=c&7; \
    uint4 dv = *(const uint4*)((P) + row*64 + c8*8); \
    *(uint4*)((char*)(Ps) + (row<<7) + ((c8<<4)^((row&7)<<4))) = dv; \
  }
#define STAGE_XS(Xs, X, b, hh, n0) \
  _Pragma("unroll") \
  for (int i=0;i<2;i++){ \
    int c=threadIdx.x+i*256, row=c>>3, c8=c&7; \
    uint4 dv = *(const uint4*)((X) + ((long)(b)*N_ + (n0)+row)*D_ + (hh)*DH_ + c8*8); \
    *(uint4*)((char*)(Xs) + (row<<7) + ((c8<<4)^((row&7)<<4))) = dv; \
  }
// staging + in-flight diag: dgL[row] = sum_d x^2 / 16 (8 lanes/row -> 3 shfl)
#define STAGE_XS_DG(Xs, X, b, hh, n0, dgL) \
  _Pragma("unroll") \
  for (int i=0;i<2;i++){ \
    int c=threadIdx.x+i*256, row=c>>3, c8=c&7; \
    uint4 dv = *(const uint4*)((X) + ((long)(b)*N_ + (n0)+row)*D_ + (hh)*DH_ + c8*8); \
    *(uint4*)((char*)(Xs) + (row<<7) + ((c8<<4)^((row&7)<<4))) = dv; \
    const u16* pe=(const u16*)&dv; \
    float sq=0.f; \
    _Pragma("unroll") \
    for (int e=0;e<8;e++){ float xv=b2f(pe[e]); sq += xv*xv; } \
    sq += __shfl_xor(sq,1); sq += __shfl_xor(sq,2); sq += __shfl_xor(sq,4); \
    if ((threadIdx.x&7)==0) (dgL)[row]=sq*0.0625f; \
  }
#define DD_MFMA(acc, Xs, Ps, w, lr, lg) \
  _Pragma("unroll") \
  for (int ks=0;ks<2;ks++){ \
    bf16x8 aF[4], bF[4]; \
    _Pragma("unroll") \
    for (int mi=0;mi<4;mi++){ \
      int row=mi*16+(lr); \
      aF[mi]=*(const bf16x8*)((const char*)(Xs) + (row<<7) + ((((ks<<2)+(lg))<<4)^((row&7)<<4))); \
    } \
    _Pragma("unroll") \
    for (int ni=0;ni<4;ni++){ \
      int row=(w)*64+ni*16+(lr); \
      bF[ni]=*(const bf16x8*)((const char*)(Ps) + (row<<7) + ((((ks<<2)+(lg))<<4)^((row&7)<<4))); \
    } \
    _Pragma("unroll") \
    for (int mi=0;mi<4;mi++) \
      _Pragma("unroll") \
      for (int ni=0;ni<4;ni++) \
        acc[mi][ni]=__builtin_amdgcn_mfma_f32_16x16x32_bf16(aF[mi],bF[ni],acc[mi][ni],0,0,0); \
  }

// ---- stab: global max of dd(K) per head -> atomicMax key ----
__global__ __launch_bounds__(256) void ddstab_k(
    const u16* __restrict__ X, const u16* __restrict__ P,
    unsigned* __restrict__ sk, int zoff)
{
  __shared__ __align__(16) char smem[46080];
  u16* Ps=(u16*)smem; u16* Xs=(u16*)(smem+36864); float* rm=(float*)(smem+45056);
  int t=threadIdx.x, w=t>>6, lane=t&63, lr=lane&15, lg=lane>>4;
  int zg=blockIdx.y+zoff, n0=blockIdx.x*64;
  int b=zg>>4, hh=zg&15;
  STAGE_PS(Ps, P); STAGE_XS(Xs, X, b, hh, n0);
  __syncthreads();
  f32x4 acc[4][4];
  #pragma unroll
  for (int mi=0;mi<4;mi++)
    #pragma unroll
    for (int ni=0;ni<4;ni++) acc[mi][ni]=(f32x4){0.f,0.f,0.f,0.f};
  DD_MFMA(acc, Xs, Ps, w, lr, lg);
  float mx = acc[0][0][0];
  #pragma unroll
  for (int mi=0;mi<4;mi++)
    #pragma unroll
    for (int ni=0;ni<4;ni++)
      #pragma unroll
      for (int r=0;r<4;r++) mx=fmaxf(mx,acc[mi][ni][r]);
  #pragma unroll
  for (int m=1;m<64;m<<=1) mx = fmaxf(mx, __shfl_xor(mx,m));
  if (lane==0) rm[w]=mx;
  __syncthreads();
  const float SN = 0.35355339059327373f;
  if (t==0) atomicMax(sk+zg, fkey(SN*fmaxf(fmaxf(rm[0],rm[1]),fmaxf(rm[2],rm[3]))));
}

// ---- fused: dd(K)+diag+exp -> kp ; ksum partial ; ctx partial = kp^T . v ----
__global__ __launch_bounds__(256) void ddctx_k(
    const u16* __restrict__ Kb, const u16* __restrict__ P,
    const u16* __restrict__ Vt, const unsigned* __restrict__ sk,
    float* __restrict__ part, float* __restrict__ kspart, int zoff)
{
  __shared__ __align__(16) char smem[54784];
  u16* Ps = (u16*)smem;               // [0,32768) per-subtile proj
  u16* Tr = (u16*)smem;               // [0,36864) kp^T overlay (256x72)
  u16* Xs = (u16*)(smem+36864);       // 8KB
  u16* Vs = (u16*)(smem+45056);       // [64][72] v^T tile (9216B -> 54272)
  float* dgL = (float*)(smem+54272);  // [64]
  int t=threadIdx.x, w=t>>6, lane=t&63, lr=lane&15, lg=lane>>4;
  int zl=blockIdx.y, zg=zl+zoff, slot=blockIdx.x;
  int b=zg>>4, hh=zg&15;
  const float SN = 0.35355339059327373f;
  float stab = fdec(sk[zg]);

  f32x4 cacc[4][4];
  #pragma unroll
  for (int mi=0;mi<4;mi++)
    #pragma unroll
    for (int ni=0;ni<4;ni++) cacc[mi][ni]=(f32x4){0.f,0.f,0.f,0.f};
  float ksp[4]={0.f,0.f,0.f,0.f};

  for (int s=0;s<4;++s){
    int n0 = slot*256 + s*64;
    STAGE_PS(Ps, P); STAGE_XS_DG(Xs, Kb, b, hh, n0, dgL);
    {
      int d=t>>2, nc=(t&3)*16;
      const u16* src = Vt + (long)zg*DH_*N_ + (long)d*N_ + n0 + nc;
      *(uint4*)&Vs[d*72+nc]   = *(const uint4*)src;
      *(uint4*)&Vs[d*72+nc+8] = *(const uint4*)(src+8);
    }
    __syncthreads();
    f32x4 acc[4][4];
    #pragma unroll
    for (int mi=0;mi<4;mi++)
      #pragma unroll
      for (int ni=0;ni<4;ni++) acc[mi][ni]=(f32x4){0.f,0.f,0.f,0.f};
    DD_MFMA(acc, Xs, Ps, w, lr, lg);
    __syncthreads();                       // Ps reads done before Tr overwrite
    #pragma unroll
    for (int mi=0;mi<4;mi++)
      #pragma unroll
      for (int ni=0;ni<4;ni++){
        int col = w*64+ni*16+lr;
        #pragma unroll
        for (int r=0;r<4;r++){
          int rw = mi*16+lg*4+r;
          float kp = 0.0625f*(expf(SN*acc[mi][ni][r] - dgL[rw] - stab) + 1e-4f);
          Tr[col*72+rw] = f2b(kp);
          ksp[ni] += kp;
        }
      }
    __syncthreads();                       // Tr ready
    #pragma unroll
    for (int ks=0;ks<2;ks++){
      bf16x8 aF[4], bF[4];
      #pragma unroll
      for (int mi=0;mi<4;mi++)
        aF[mi]=*(const bf16x8*)(Tr + (w*64+mi*16+lr)*72 + ks*32 + lg*8);
      #pragma unroll
      for (int ni=0;ni<4;ni++)
        bF[ni]=*(const bf16x8*)(Vs + (ni*16+lr)*72 + ks*32 + lg*8);
      #pragma unroll
      for (int mi=0;mi<4;mi++)
        #pragma unroll
        for (int ni=0;ni<4;ni++)
          cacc[mi][ni]=__builtin_amdgcn_mfma_f32_16x16x32_bf16(aF[mi],bF[ni],cacc[mi][ni],0,0,0);
    }
    __syncthreads();                       // before next subtile restage
  }
  #pragma unroll
  for (int ni=0;ni<4;ni++){
    ksp[ni] += __shfl_xor(ksp[ni],16);
    ksp[ni] += __shfl_xor(ksp[ni],32);
  }
  if (lane<16){
    float* kb_ = kspart + ((long)zl*8+slot)*256;
    #pragma unroll
    for (int ni=0;ni<4;ni++) kb_[w*64+ni*16+lane] = ksp[ni];
  }
  float* pb = part + ((long)zl*8+slot)*16384;
  #pragma unroll
  for (int mi=0;mi<4;mi++)
    #pragma unroll
    for (int ni=0;ni<4;ni++){
      int d = ni*16+lr;
      #pragma unroll
      for (int r=0;r<4;r++){
        int m = w*64+mi*16+lg*4+r;
        pb[m*64+d] = cacc[mi][ni][r];
      }
    }
}

// ---- reduce 8 slots -> ksm[z][m] fp32 ; ctxT[z][d][m] bf16 (transposed) ----
__global__ __launch_bounds__(256) void ctxred2_k(
    const float* __restrict__ part, const float* __restrict__ kspart,
    u16* __restrict__ ctxT, float* __restrict__ ksm)
{
  int z = blockIdx.x, t = threadIdx.x;
  const float* pz = part + (long)z*8*16384;
  const float* kz = kspart + (long)z*8*256;
  float s=0.f;
  #pragma unroll
  for (int s8=0;s8<8;s8++) s += kz[s8*256+t];
  ksm[(long)z*256+t]=s;
  f32x4 r4[16];
  #pragma unroll
  for (int j=0;j<16;j++) r4[j] = *(const f32x4*)(pz + (long)t*64 + j*4);
  #pragma unroll
  for (int s8=1;s8<8;s8++){
    const float* ps = pz + (long)s8*16384 + (long)t*64;
    #pragma unroll
    for (int j=0;j<16;j++) r4[j] += *(const f32x4*)(ps + j*4);
  }
  u16 rb[64];
  #pragma unroll
  for (int j=0;j<16;j++){
    rb[j*4+0]=f2b(r4[j][0]); rb[j*4+1]=f2b(r4[j][1]);
    rb[j*4+2]=f2b(r4[j][2]); rb[j*4+3]=f2b(r4[j][3]);
  }
  __shared__ __align__(16) u16 TT[64][72];
  u16* co = ctxT + (long)z*16384;
  for (int c=0;c<4;c++){
    __syncthreads();
    if ((t>>6)==c){
      int r=t&63;
      #pragma unroll
      for (int j=0;j<64;j+=8) *(uint4*)&TT[r][j] = *(const uint4*)&rb[j];
    }
    __syncthreads();
    int d=t>>2, mq=(t&3)*16;
    union { u16 u[16]; uint4 q[2]; } tmp;
    #pragma unroll
    for (int j=0;j<16;j++) tmp.u[j]=TT[mq+j][d];
    *(uint4*)(co + d*256 + c*64 + mq)     = tmp.q[0];
    *(uint4*)(co + d*256 + c*64 + mq + 8) = tmp.q[1];
  }
}

// ---- fused: dd(Q)+diag+rowmax+exp -> qp(LDS) ; dinv in-block ; out = dinv*(qp.ctxT) ----
__global__ __launch_bounds__(256) void ddq_attn_k(
    const u16* __restrict__ Qb, const u16* __restrict__ P,
    const float* __restrict__ ksm, const u16* __restrict__ ctxT,
    u16* __restrict__ at, int zoff)
{
  __shared__ __align__(16) char smem[46336];
  u16*   Ps  = (u16*)smem;                 // dd phase
  u16*   qpL = (u16*)smem;                 // [64][264] overlay (33792B)
  float* rdot= (float*)(smem+33792);       // [256]
  float* dnvs= (float*)(smem+34816);       // [64]
  u16*   Xs  = (u16*)(smem+36864);
  float* rm  = (float*)(smem+45056);       // [256]
  float* dgL = (float*)(smem+46080);       // [64]
  int t=threadIdx.x, w=t>>6, lane=t&63, lr=lane&15, lg=lane>>4;
  int zl=blockIdx.y, zg=zl+zoff, n0=blockIdx.x*64;
  int b=zg>>4, hh=zg&15;
  const float SN = 0.35355339059327373f;

  STAGE_PS(Ps, P); STAGE_XS_DG(Xs, Qb, b, hh, n0, dgL);
  __syncthreads();
  f32x4 acc[4][4];
  #pragma unroll
  for (int mi=0;mi<4;mi++)
    #pragma unroll
    for (int ni=0;ni<4;ni++) acc[mi][ni]=(f32x4){0.f,0.f,0.f,0.f};
  DD_MFMA(acc, Xs, Ps, w, lr, lg);
  float rmx[4][4];
  #pragma unroll
  for (int mi=0;mi<4;mi++)
    #pragma unroll
    for (int r=0;r<4;r++){
      float v = acc[mi][0][r];
      #pragma unroll
      for (int ni=1;ni<4;ni++) v=fmaxf(v, acc[mi][ni][r]);
      #pragma unroll
      for (int m=1;m<16;m<<=1) v = fmaxf(v, __shfl_xor(v,m));
      rmx[mi][r]=v;
    }
  if (lr==0){
    #pragma unroll
    for (int mi=0;mi<4;mi++)
      #pragma unroll
      for (int r=0;r<4;r++) rm[w*64 + mi*16 + lg*4 + r] = rmx[mi][r];
  }
  __syncthreads();                         // Ps reads done; rm/dgL ready
  const float* ksz = ksm + (long)zl*256;
  float kcol[4];
  #pragma unroll
  for (int ni=0;ni<4;ni++) kcol[ni] = ksz[w*64+ni*16+lr];
  float rd[4][4];
  #pragma unroll
  for (int mi=0;mi<4;mi++)
    #pragma unroll
    for (int r=0;r<4;r++){
      int rw = mi*16+lg*4+r;
      float st = fmaxf(fmaxf(rm[rw],rm[64+rw]),fmaxf(rm[128+rw],rm[192+rw]));
      float dgv = dgL[rw];
      float rsum = 0.f;
      #pragma unroll
      for (int ni=0;ni<4;ni++){
        int col = w*64+ni*16+lr;
        float qpv = 0.0625f*(expf(SN*acc[mi][ni][r] - dgv - SN*st) + 1e-4f);
        qpL[rw*264+col] = f2b(qpv);
        rsum += qpv*kcol[ni];
      }
      rd[mi][r]=rsum;
    }
  #pragma unroll
  for (int mi=0;mi<4;mi++)
    #pragma unroll
    for (int r=0;r<4;r++){
      #pragma unroll
      for (int m=1;m<16;m<<=1) rd[mi][r] += __shfl_xor(rd[mi][r],m);
    }
  if (lr==0){
    #pragma unroll
    for (int mi=0;mi<4;mi++)
      #pragma unroll
      for (int r=0;r<4;r++) rdot[w*64 + mi*16+lg*4+r] = rd[mi][r];
  }
  __syncthreads();
  if (t<64) dnvs[t] = 1.0f/(rdot[t]+rdot[64+t]+rdot[128+t]+rdot[192+t]);
  __syncthreads();
  const u16* cz = ctxT + (long)zl*16384;
  f32x4 aacc[4];
  #pragma unroll
  for (int ni=0;ni<4;ni++) aacc[ni]=(f32x4){0.f,0.f,0.f,0.f};
  #pragma unroll
  for (int ks=0;ks<8;ks++){
    bf16x8 aF = *(const bf16x8*)(qpL + (w*16+lr)*264 + ks*32 + lg*8);
    #pragma unroll
    for (int ni=0;ni<4;ni++){
      bf16x8 bF = *(const bf16x8*)(cz + (ni*16+lr)*256 + ks*32 + lg*8);
      aacc[ni]=__builtin_amdgcn_mfma_f32_16x16x32_bf16(aF,bF,aacc[ni],0,0,0);
    }
  }
  #pragma unroll
  for (int ni=0;ni<4;ni++){
    #pragma unroll
    for (int r=0;r<4;r++){
      int n = n0 + w*16 + lg*4 + r;
      at[((long)b*N_ + n)*D_ + hh*64 + ni*16 + lr] = f2b(aacc[ni][r]*dnvs[w*16+lg*4+r]);
    }
  }
}

// ---------------- generic bf16 MFMA GEMM: C = A(MxK) * W(NxK)^T ----------------
// Both operands via global_load_lds (linear LDS dest) with pre-swizzled GLOBAL
// source column; reads apply the same XOR -> 2-way bank aliasing = free.
// EPI 0: bf16 = acc+bias   1: f32 resid += acc+bias   2: bf16 = gelu(acc+bias)
// EPI 6: fused QKV: route by col>>10 into 3 contiguous buffers, bias from 3 ptrs
template<int BM,int BN,int WR,int WC,int EPI,bool XS>
__global__ __launch_bounds__(256) void gemm_k(
    const u16* __restrict__ A, int lda,
    const u16* __restrict__ W, int ldw,
    const float* __restrict__ bias, const float* __restrict__ biasK, const float* __restrict__ biasV,
    void* __restrict__ Cv, int ldc, int K)
{
  static_assert(WR*WC==4, "4 waves");
  constexpr int WM=BM/WR, WN=BN/WC, MI=WM/16, NI=WN/16;
  __shared__ __align__(16) u16 As[BM*64];
  __shared__ __align__(16) u16 Ws[BN*64];
  int t=threadIdx.x;
  int bx, by;
  if (XS){
    unsigned gx=gridDim.x, flat=blockIdx.y*gx+blockIdx.x;
    unsigned cpx=(gx*gridDim.y)>>3;
    unsigned s=(flat&7)*cpx + (flat>>3);
    bx = s % gx; by = s / gx;
  } else { bx = blockIdx.x; by = blockIdx.y; }
  const u16* Ab = A + (long)by*BM*lda;
  const u16* Wb = W + (long)bx*BN*ldw;
  int w=t>>6, lane=t&63, lr=lane&15, lg=lane>>4;
  int wr=w/WC, wc=w%WC;
  int srow=lane>>3, swcol=((lane&7)^srow)*8;   // swizzled global source col
  f32x4 acc[MI][NI];
  #pragma unroll
  for (int mi=0;mi<MI;mi++)
    #pragma unroll
    for(int ni=0;ni<NI;ni++) acc[mi][ni]=(f32x4){0.f,0.f,0.f,0.f};

  for (int k0=0;k0<K;k0+=64){
    #pragma unroll
    for (int i=0;i<BM/32;i++){
      int rb=w*(BM/4)+i*8;
      gload16(Ab + (long)(rb+srow)*lda + k0 + swcol, As + rb*64);
    }
    #pragma unroll
    for (int i=0;i<BN/32;i++){
      int rb=w*(BN/4)+i*8;
      gload16(Wb + (long)(rb+srow)*ldw + k0 + swcol, Ws + rb*64);
    }
    __syncthreads();
    #pragma unroll
    for (int ks=0;ks<2;ks++){
      bf16x8 aF[MI], bF[NI];
      #pragma unroll
      for (int mi=0;mi<MI;mi++){
        int row=wr*WM+mi*16+lr;
        aF[mi]=*(const bf16x8*)((const char*)As + (row<<7) + ((((ks<<2)+lg)<<4)^((row&7)<<4)));
      }
      #pragma unroll
      for (int ni=0;ni<NI;ni++){
        int row=wc*WN+ni*16+lr;
        bF[ni]=*(const bf16x8*)((const char*)Ws + (row<<7) + ((((ks<<2)+lg)<<4)^((row&7)<<4)));
      }
      #pragma unroll
      for (int mi=0;mi<MI;mi++)
        #pragma unroll
        for (int ni=0;ni<NI;ni++)
          acc[mi][ni]=__builtin_amdgcn_mfma_f32_16x16x32_bf16(aF[mi],bF[ni],acc[mi][ni],0,0,0);
    }
    __syncthreads();
  }

  #pragma unroll
  for (int mi=0;mi<MI;mi++){
    #pragma unroll
    for (int ni=0;ni<NI;ni++){
      int col = bx*BN + wc*WN + ni*16 + lr;
      float bv = 0.0f;
      if (EPI==6){
        int seg = col>>10;
        const float* bp = (seg==0)?bias:((seg==1)?biasK:biasV);
        bv = bp[col&1023];
      } else if (EPI<=2){
        bv = bias[col];
      }
      #pragma unroll
      for (int r=0;r<4;r++){
        int row = by*BM + wr*WM + mi*16 + lg*4 + r;
        float v = acc[mi][ni][r];
        if (EPI==0){
          ((u16*)Cv)[(long)row*ldc + col] = f2b(v+bv);
        } else if (EPI==1){
          ((float*)Cv)[(long)row*ldc + col] += v+bv;
        } else if (EPI==2){
          float u=v+bv;
          ((u16*)Cv)[(long)row*ldc + col] = f2b(0.5f*u*(1.0f+erff(u*0.70710678118654752f)));
        } else {
          int seg = col>>10, c = col&1023;
          ((u16*)Cv)[(long)seg*((long)ROWS_*D_) + (long)row*D_ + c] = f2b(v+bv);
        }
      }
    }
  }
}

// =================================================================
struct WS {
  u16 *wbuf, *pjb, *hb, *qb, *kb, *pbuf, *sh16, *ctxT;
  float *part, *kspart, *ksm; unsigned* sky;
  size_t total;
};
static WS plan_ws(char* base, int allW, int CH){
  WS w; size_t off=0;
  auto al=[&](size_t b)->char*{ char* p=base+off; off=(off+b+255)&~(size_t)255; return p; };
  const size_t TB=(size_t)ROWS_*D_*2;
  w.wbuf=(u16*)al((allW?6ull*L_:6ull)*WN_*2);
  w.pjb =(u16*)al((size_t)L_*M_*DH_*2);
  w.hb  =(u16*)al(TB);
  // qb, kb, pbuf MUST be contiguous (fused-QKV epilogue: seg*ROWS_*D_)
  w.qb  =(u16*)al(TB);
  w.kb  =(u16*)al(TB);
  w.pbuf=(u16*)al(TB);                  // hosts vb (seg 2)
  w.sh16=(u16*)al(TB);                  // vt / FFN intermediate
  w.part=(float*)al((size_t)CH*8*M_*DH_*4);
  w.kspart=(float*)al((size_t)CH*8*M_*4);
  w.ctxT=(u16*)al((size_t)BH_*DH_*M_*2);
  w.ksm =(float*)al((size_t)BH_*M_*4);
  w.sky =(unsigned*)al((size_t)L_*BH_*4);
  w.total=off;
  return w;
}

extern "C" void kernel_launch(void* const* d_in, const int* in_sizes, int n_in,
                              void* d_out, int out_size, void* d_ws, size_t ws_size,
                              hipStream_t stream)
{
  const float* x    = (const float*)d_in[0];
  const float* proj = (const float*)d_in[1];
  const float* ln1g = (const float*)d_in[2];
  const float* ln1b = (const float*)d_in[3];
  const float* Wq   = (const float*)d_in[4];
  const float* bq   = (const float*)d_in[5];
  const float* Wk   = (const float*)d_in[6];
  const float* bk   = (const float*)d_in[7];
  const float* Wv   = (const float*)d_in[8];
  const float* bv   = (const float*)d_in[9];
  const float* Wo   = (const float*)d_in[10];
  const float* bo   = (const float*)d_in[11];
  const float* ln2g = (const float*)d_in[12];
  const float* ln2b = (const float*)d_in[13];
  const float* W1   = (const float*)d_in[14];
  const float* b1   = (const float*)d_in[15];
  const float* W2   = (const float*)d_in[16];
  const float* b2   = (const float*)d_in[17];

  char* base=(char*)d_ws;
  int allW=1, CH=64;
  WS w = plan_ws(base, 1, 64);
  if (w.total > ws_size){ CH=16; w = plan_ws(base, 1, 16); }
  if (w.total > ws_size){ allW=0; w = plan_ws(base, 0, 16); }
  if (w.total > ws_size){
    fillf_k<<<(out_size+255)/256,256,0,stream>>>((float*)d_out,(long)out_size,(float)(ws_size>>20));
    return;
  }
  const int NCH = BH_/CH;

  u16* vb = w.pbuf;     // V output (seg 2 of fused QKV)
  u16* vt = w.sh16;     // v_t, dead before FFN intermediate
  u16* at = w.hb;       // attn out, hb dead between QKV-GEMM and ln2
  u16* tm = w.sh16;     // FFN intermediate

  wcvt_k<<<(L_*M_*DH_/4+255)/256,256,0,stream>>>(proj,w.pjb,(long)L_*M_*DH_);
  hipMemsetAsync(w.sky, 0, (size_t)L_*BH_*4, stream);
  if (allW){
    const long na = (long)L_*WN_;
    const int g2 = (int)(na/4/256);
    wcvt2_k<<<g2,256,0,stream>>>(Wq, w.wbuf,         na);
    wcvt2_k<<<g2,256,0,stream>>>(Wk, w.wbuf+WN_,     na);
    wcvt2_k<<<g2,256,0,stream>>>(Wv, w.wbuf+2l*WN_,  na);
    wcvt2_k<<<g2,256,0,stream>>>(Wo, w.wbuf+3l*WN_,  na);
    wcvt2_k<<<g2,256,0,stream>>>(W1, w.wbuf+4l*WN_,  na);
    wcvt2_k<<<g2,256,0,stream>>>(W2, w.wbuf+5l*WN_,  na);
  }
  hipMemcpyAsync(d_out, x, (size_t)ROWS_*D_*4, hipMemcpyDeviceToDevice, stream);
  float* Xc = (float*)d_out;

  const long wn = (long)WN_;
  const int wg = (int)(wn/4/256);
  dim3 gBig(D_/128, ROWS_/64, 1);        // 8 x 128 = 1024 blocks (64x128 tile)
  dim3 gQKV(3*D_/128, ROWS_/128, 1);     // 24 x 64 = 1536 blocks (128x128 tile)

  for (int l=0;l<L_;l++){
    u16* lw = w.wbuf + (allW ? (size_t)l*6*wn : 0);
    u16* wqkv=lw;  u16* wo=lw+3*wn;  u16* w1=lw+4*wn;  u16* w2=lw+5*wn;
    if (!allW){
      wcvt_k<<<wg,256,0,stream>>>(Wq+(size_t)l*wn,lw,wn);
      wcvt_k<<<wg,256,0,stream>>>(Wk+(size_t)l*wn,lw+wn,wn);
      wcvt_k<<<wg,256,0,stream>>>(Wv+(size_t)l*wn,lw+2*wn,wn);
      wcvt_k<<<wg,256,0,stream>>>(Wo+(size_t)l*wn,wo,wn);
      wcvt_k<<<wg,256,0,stream>>>(W1+(size_t)l*wn,w1,wn);
      wcvt_k<<<wg,256,0,stream>>>(W2+(size_t)l*wn,w2,wn);
    }
    const u16* pj = w.pjb + (size_t)l*M_*DH_;
    unsigned* skl = w.sky + (size_t)l*BH_;

    ln_k<<<ROWS_,256,0,stream>>>(Xc, ln1g+(size_t)l*D_, ln1b+(size_t)l*D_, w.hb);
    gemm_k<128,128,2,2,6,true><<<gQKV,256,0,stream>>>(w.hb,D_, wqkv,D_,
        bq+(size_t)l*D_, bk+(size_t)l*D_, bv+(size_t)l*D_, w.qb,D_,D_);
    vt_k<<<dim3(N_/64,BH_),256,0,stream>>>(vb, vt);

    for (int ch=0; ch<NCH; ch++){
      int zoff = ch*CH;
      ddstab_k<<<dim3(N_/64,CH),256,0,stream>>>(w.kb, pj, skl, zoff);
      ddctx_k<<<dim3(8,CH),256,0,stream>>>(w.kb, pj, vt, skl, w.part, w.kspart, zoff);
      ctxred2_k<<<CH,256,0,stream>>>(w.part, w.kspart,
                                     w.ctxT+(long)zoff*DH_*M_, w.ksm+(long)zoff*M_);
      ddq_attn_k<<<dim3(N_/64,CH),256,0,stream>>>(w.qb, pj,
                                                  w.ksm+(long)zoff*M_,
                                                  w.ctxT+(long)zoff*DH_*M_, at, zoff);
    }

    gemm_k<64,128,1,4,1,true><<<gBig,256,0,stream>>>(at,D_, wo,D_,
        bo+(size_t)l*D_, nullptr, nullptr, Xc,D_,D_);
    ln_k<<<ROWS_,256,0,stream>>>(Xc, ln2g+(size_t)l*D_, ln2b+(size_t)l*D_, w.hb);
    gemm_k<64,128,1,4,2,true><<<gBig,256,0,stream>>>(w.hb,D_, w1,D_,
        b1+(size_t)l*D_, nullptr, nullptr, tm,D_,D_);
    gemm_k<64,128,1,4,1,true><<<gBig,256,0,stream>>>(tm,D_, w2,D_,
        b2+(size_t)l*D_, nullptr, nullptr, Xc,D_,D_);
  }
}